// Round 1
// baseline (4999.832 us; speedup 1.0000x reference)
//
#include <hip/hip_runtime.h>
#include <cstdint>
#include <cstddef>

// Problem constants
#define LN_ 2
#define HH 8
#define DM 1024
#define FFN_ 4096
#define HDD 128
#define SS 2048
#define BB 2
#define RR (BB*SS)   // 4096 rows total

__device__ inline float silu_f(float x) { return x / (1.0f + expf(-x)); }

__device__ inline float dot4acc(float4 a, float4 b, float acc) {
  return fmaf(a.w, b.w, fmaf(a.z, b.z, fmaf(a.y, b.y, fmaf(a.x, b.x, acc))));
}

__device__ inline float4 fma4(float s, float4 v, float4 a) {
  a.x = fmaf(s, v.x, a.x); a.y = fmaf(s, v.y, a.y);
  a.z = fmaf(s, v.z, a.z); a.w = fmaf(s, v.w, a.w);
  return a;
}

// ---------------- xPos tables + decay log-gammas (fp64, matches numpy ref) ---
__global__ void init_tables_k(float* __restrict__ sq, float* __restrict__ cq,
                              float* __restrict__ sk, float* __restrict__ ck,
                              float* __restrict__ lng) {
  int s = blockIdx.x;      // 0..2047
  int k = threadIdx.x;     // 0..127
  int j = k >> 1;          // dup: repeat(…,2)
  double sv    = (2.0 * j + 0.4 * HDD) / (1.4 * HDD);
  double p     = (double)s / 512.0;
  double scale = pow(sv, p);
  double invf  = pow(10000.0, -((double)j) / 64.0);
  double ang   = (double)s * invf;
  double sn = sin(ang), cs = cos(ang);
  size_t idx = (size_t)s * HDD + k;
  sq[idx] = (float)(sn * scale);
  cq[idx] = (float)(cs * scale);
  sk[idx] = (float)(sn / scale);
  ck[idx] = (float)(cs / scale);
  if (s == 0 && k < HH) {
    double a0 = log(1.0 / 32.0), a1 = log(1.0 / 512.0);
    double x = a0 + (a1 - a0) * ((double)k / 7.0);
    lng[k] = (float)log(1.0 - exp(x));
  }
}

// ---------------- LayerNorm: one block per row (D=1024), 256 thr -------------
__global__ __launch_bounds__(256) void layernorm_k(
    const float* __restrict__ X, const float* __restrict__ w,
    const float* __restrict__ b, float* __restrict__ O) {
  const int row = blockIdx.x, tid = threadIdx.x;
  const float* x = X + (size_t)row * DM;
  float4 v = *(const float4*)(x + tid * 4);
  float s = v.x + v.y + v.z + v.w;
  float q = v.x * v.x + v.y * v.y + v.z * v.z + v.w * v.w;
#pragma unroll
  for (int o = 32; o > 0; o >>= 1) { s += __shfl_xor(s, o); q += __shfl_xor(q, o); }
  __shared__ float ss[4], qq[4];
  if ((tid & 63) == 0) { ss[tid >> 6] = s; qq[tid >> 6] = q; }
  __syncthreads();
  float S  = ss[0] + ss[1] + ss[2] + ss[3];
  float Qs = qq[0] + qq[1] + qq[2] + qq[3];
  float mu  = S * (1.0f / DM);
  float var = Qs * (1.0f / DM) - mu * mu;
  float rs  = 1.0f / sqrtf(var + 1e-5f);
  float4 wv = *(const float4*)(w + tid * 4);
  float4 bv = *(const float4*)(b + tid * 4);
  float4 o;
  o.x = (v.x - mu) * rs * wv.x + bv.x;
  o.y = (v.y - mu) * rs * wv.y + bv.y;
  o.z = (v.z - mu) * rs * wv.z + bv.z;
  o.w = (v.w - mu) * rs * wv.w + bv.w;
  *(float4*)(O + (size_t)row * DM + tid * 4) = o;
}

// ---------------- SGEMM 128x64x16, templated epilogue ------------------------
// MODE 0: QKV plain (V)            -> C[b][h][s][k]
// MODE 1: QKV + rotary (Q tables)  -> C[b][h][s][k]
// MODE 2: QKV + rotary (K tables)  -> C[b][h][s][k]
// MODE 3: silu(acc)                -> C row-major
// MODE 4: silu(acc + bias)         -> C row-major
// MODE 5: acc + resid              -> C row-major
// MODE 6: acc + bias + resid       -> C row-major
template <int MODE>
__global__ __launch_bounds__(256) void gemm_k(
    const float* __restrict__ A, const float* __restrict__ Bw, float* __restrict__ C,
    const float* __restrict__ bias, const float* __restrict__ resid,
    const float* __restrict__ tsin, const float* __restrict__ tcos,
    int N, int K) {
  __shared__ float As[16][132];  // [k][m], +4 pad
  __shared__ float Bs[16][68];   // [k][n], +4 pad
  const int tid = threadIdx.x;
  const int tx = tid & 15, ty = tid >> 4;
  const int m0 = blockIdx.y * 128;
  const int n0 = blockIdx.x * 64;
  const int ar  = tid >> 2;
  const int ak  = (tid & 3) << 2;
  const int bkk = tid >> 4;
  const int bc  = (tid & 15) << 2;

  float acc[8][4] = {};

  for (int k0 = 0; k0 < K; k0 += 16) {
    // global prefetch into registers (overlaps with previous tile's compute)
    float4 a0 = *(const float4*)(A + (size_t)(m0 + ar) * K + k0 + ak);
    float4 a1 = *(const float4*)(A + (size_t)(m0 + ar + 64) * K + k0 + ak);
    float4 b0;
    if (MODE <= 2) {
      int n = n0 + bc;  // B is [h][K][128] blocks; a 64-wide tile stays in one head
      b0 = *(const float4*)(Bw + (size_t)(n >> 7) * K * 128 +
                            (size_t)(k0 + bkk) * 128 + (n & 127));
    } else {
      b0 = *(const float4*)(Bw + (size_t)(k0 + bkk) * N + n0 + bc);
    }
    __syncthreads();
    As[ak + 0][ar] = a0.x; As[ak + 1][ar] = a0.y;
    As[ak + 2][ar] = a0.z; As[ak + 3][ar] = a0.w;
    As[ak + 0][ar + 64] = a1.x; As[ak + 1][ar + 64] = a1.y;
    As[ak + 2][ar + 64] = a1.z; As[ak + 3][ar + 64] = a1.w;
    *(float4*)&Bs[bkk][bc] = b0;
    __syncthreads();
#pragma unroll
    for (int kk = 0; kk < 16; ++kk) {
      float4 av0 = *(const float4*)&As[kk][ty * 4];
      float4 av1 = *(const float4*)&As[kk][ty * 4 + 64];
      float4 bv  = *(const float4*)&Bs[kk][tx * 4];
      float aa[8]  = {av0.x, av0.y, av0.z, av0.w, av1.x, av1.y, av1.z, av1.w};
      float bb4[4] = {bv.x, bv.y, bv.z, bv.w};
#pragma unroll
      for (int i = 0; i < 8; ++i)
#pragma unroll
        for (int jj = 0; jj < 4; ++jj)
          acc[i][jj] = fmaf(aa[i], bb4[jj], acc[i][jj]);
    }
  }

  const int gc = n0 + tx * 4;
#pragma unroll
  for (int i = 0; i < 8; ++i) {
    int rl = (i < 4) ? (ty * 4 + i) : (ty * 4 + 60 + i);  // +64 block for i>=4
    int gr = m0 + rl;
    float4 o = {acc[i][0], acc[i][1], acc[i][2], acc[i][3]};
    if (MODE == 1 || MODE == 2) {
      int s  = gr & (SS - 1);
      int k2 = gc & 127;
      float4 sn = *(const float4*)(tsin + (size_t)s * HDD + k2);
      float4 cn = *(const float4*)(tcos + (size_t)s * HDD + k2);
      float4 r;
      r.x = o.x * cn.x - o.y * sn.x;   // even: q*cos - q_odd*sin
      r.y = o.y * cn.y + o.x * sn.y;   // odd : q*cos + q_even*sin
      r.z = o.z * cn.z - o.w * sn.z;
      r.w = o.w * cn.w + o.z * sn.w;
      o = r;
    }
    if (MODE == 3) {
      o.x = silu_f(o.x); o.y = silu_f(o.y); o.z = silu_f(o.z); o.w = silu_f(o.w);
    }
    if (MODE == 4) {
      float4 bz = *(const float4*)(bias + gc);
      o.x = silu_f(o.x + bz.x); o.y = silu_f(o.y + bz.y);
      o.z = silu_f(o.z + bz.z); o.w = silu_f(o.w + bz.w);
    }
    if (MODE == 5) {
      float4 rz = *(const float4*)(resid + (size_t)gr * N + gc);
      o.x += rz.x; o.y += rz.y; o.z += rz.z; o.w += rz.w;
    }
    if (MODE == 6) {
      float4 bz = *(const float4*)(bias + gc);
      float4 rz = *(const float4*)(resid + (size_t)gr * N + gc);
      o.x += bz.x + rz.x; o.y += bz.y + rz.y;
      o.z += bz.z + rz.z; o.w += bz.w + rz.w;
    }
    if (MODE <= 2) {
      int bI = gr >> 11, s = gr & (SS - 1);
      int h  = gc >> 7,  k2 = gc & 127;
      *(float4*)(C + (((size_t)bI * HH + h) * SS + s) * HDD + k2) = o;
    } else {
      *(float4*)(C + (size_t)gr * N + gc) = o;
    }
  }
}

// ---------------- Retention (decay-masked attention), fused, no SxS ----------
// grid (32, H, B); Q tile 64 rows, K/V tiles 32 rows; LDS ~59 KB.
__global__ __launch_bounds__(256) void attn_k(
    const float* __restrict__ Q, const float* __restrict__ Kp,
    const float* __restrict__ V, const float* __restrict__ lng,
    float* __restrict__ Y) {
  const int qt = 31 - blockIdx.x;  // heavy blocks dispatch first
  const int h  = blockIdx.y, bI = blockIdx.z;
  const float lg = lng[h];
  const size_t base = ((size_t)bI * HH + h) * SS * HDD;
  __shared__ float Qs[64][132];
  __shared__ float KVs[32][136];
  __shared__ float Sls[64][36];
  const int tid = threadIdx.x;
  const float* Qp = Q + base + (size_t)qt * 64 * HDD;
#pragma unroll
  for (int it = 0; it < 8; ++it) {
    int idx = tid + it * 256;
    int r = idx >> 5, c4 = (idx & 31) << 2;
    *(float4*)&Qs[r][c4] = *(const float4*)(Qp + (size_t)r * HDD + c4);
  }
  float4 acc[4][2] = {};
  const int rg = tid >> 4, cg = tid & 15;  // rows rg*4..+3 ; PV cols cg*8..+7
  const int nkt = 2 * qt + 2;
  for (int kt = 0; kt < nkt; ++kt) {
    const int m0 = kt * 32;
    __syncthreads();  // prior PV reads of KVs/Sls complete
#pragma unroll
    for (int it = 0; it < 4; ++it) {
      int idx = tid + it * 256;
      int r = idx >> 5, c4 = (idx & 31) << 2;
      *(float4*)&KVs[r][c4] = *(const float4*)(Kp + base + (size_t)(m0 + r) * HDD + c4);
    }
    __syncthreads();
    float sc[4][2] = {};
#pragma unroll
    for (int d4 = 0; d4 < 32; ++d4) {
      int d = d4 * 4;
      float4 k0 = *(const float4*)&KVs[cg * 2 + 0][d];
      float4 k1 = *(const float4*)&KVs[cg * 2 + 1][d];
      float4 q0 = *(const float4*)&Qs[rg * 4 + 0][d];
      float4 q1 = *(const float4*)&Qs[rg * 4 + 1][d];
      float4 q2 = *(const float4*)&Qs[rg * 4 + 2][d];
      float4 q3 = *(const float4*)&Qs[rg * 4 + 3][d];
      sc[0][0] = dot4acc(q0, k0, sc[0][0]); sc[0][1] = dot4acc(q0, k1, sc[0][1]);
      sc[1][0] = dot4acc(q1, k0, sc[1][0]); sc[1][1] = dot4acc(q1, k1, sc[1][1]);
      sc[2][0] = dot4acc(q2, k0, sc[2][0]); sc[2][1] = dot4acc(q2, k1, sc[2][1]);
      sc[3][0] = dot4acc(q3, k0, sc[3][0]); sc[3][1] = dot4acc(q3, k1, sc[3][1]);
    }
    const int nb = qt * 64 + rg * 4;
#pragma unroll
    for (int i = 0; i < 4; ++i)
#pragma unroll
      for (int j = 0; j < 2; ++j) {
        int n = nb + i, m = m0 + cg * 2 + j;
        float dmul = (n >= m) ? expf((float)(n - m) * lg) : 0.0f;
        sc[i][j] *= dmul;
      }
    __syncthreads();  // done reading K from KVs
#pragma unroll
    for (int i = 0; i < 4; ++i) {
      Sls[rg * 4 + i][cg * 2 + 0] = sc[i][0];
      Sls[rg * 4 + i][cg * 2 + 1] = sc[i][1];
    }
#pragma unroll
    for (int it = 0; it < 4; ++it) {  // V tile overwrites K tile
      int idx = tid + it * 256;
      int r = idx >> 5, c4 = (idx & 31) << 2;
      *(float4*)&KVs[r][c4] = *(const float4*)(V + base + (size_t)(m0 + r) * HDD + c4);
    }
    __syncthreads();
#pragma unroll 8
    for (int j = 0; j < 32; ++j) {
      float s0 = Sls[rg * 4 + 0][j];
      float s1 = Sls[rg * 4 + 1][j];
      float s2 = Sls[rg * 4 + 2][j];
      float s3 = Sls[rg * 4 + 3][j];
      float4 v0 = *(const float4*)&KVs[j][cg * 8];
      float4 v1 = *(const float4*)&KVs[j][cg * 8 + 4];
      acc[0][0] = fma4(s0, v0, acc[0][0]); acc[0][1] = fma4(s0, v1, acc[0][1]);
      acc[1][0] = fma4(s1, v0, acc[1][0]); acc[1][1] = fma4(s1, v1, acc[1][1]);
      acc[2][0] = fma4(s2, v0, acc[2][0]); acc[2][1] = fma4(s2, v1, acc[2][1]);
      acc[3][0] = fma4(s3, v0, acc[3][0]); acc[3][1] = fma4(s3, v1, acc[3][1]);
    }
  }
#pragma unroll
  for (int i = 0; i < 4; ++i) {
    size_t row = (size_t)bI * SS + qt * 64 + rg * 4 + i;
    float* dst = Y + row * DM + h * HDD + cg * 8;
    *(float4*)dst       = acc[i][0];
    *(float4*)(dst + 4) = acc[i][1];
  }
}

// ---------------- GroupNorm(HD=128 per head) * gate, in place ---------------
__global__ __launch_bounds__(256) void gn_gate_k(
    float* __restrict__ Y, const float* __restrict__ w, const float* __restrict__ b,
    const float* __restrict__ G) {
  int g    = blockIdx.x * 4 + (threadIdx.x >> 6);  // group = (b*S+s)*H + h
  int lane = threadIdx.x & 63;
  float2 v = *(const float2*)(Y + (size_t)g * HDD + lane * 2);
  float s = v.x + v.y, q = v.x * v.x + v.y * v.y;
#pragma unroll
  for (int o = 32; o > 0; o >>= 1) { s += __shfl_xor(s, o); q += __shfl_xor(q, o); }
  float mu  = s * (1.0f / HDD);
  float var = q * (1.0f / HDD) - mu * mu;
  float rs  = 1.0f / sqrtf(var + 1e-5f);
  int col = (g & 7) * HDD + lane * 2;
  float2 wv = *(const float2*)(w + col);
  float2 bv = *(const float2*)(b + col);
  float2 gv = *(const float2*)(G + (size_t)g * HDD + lane * 2);
  float2 o2;
  o2.x = ((v.x - mu) * rs * wv.x + bv.x) * gv.x;
  o2.y = ((v.y - mu) * rs * wv.y + bv.y) * gv.y;
  *(float2*)(Y + (size_t)g * HDD + lane * 2) = o2;
}

// ---------------- driver -----------------------------------------------------
extern "C" void kernel_launch(void* const* d_in, const int* in_sizes, int n_in,
                              void* d_out, int out_size, void* d_ws, size_t ws_size,
                              hipStream_t stream) {
  (void)in_sizes; (void)n_in; (void)out_size; (void)ws_size;
  const float* X0   = (const float*)d_in[0];
  const float* ln1w = (const float*)d_in[1];
  const float* ln1b = (const float*)d_in[2];
  const float* ln2w = (const float*)d_in[3];
  const float* ln2b = (const float*)d_in[4];
  const float* WQ   = (const float*)d_in[5];
  const float* WK   = (const float*)d_in[6];
  const float* WV   = (const float*)d_in[7];
  const float* gnw  = (const float*)d_in[8];
  const float* gnb  = (const float*)d_in[9];
  const float* WG   = (const float*)d_in[10];
  const float* WO   = (const float*)d_in[11];
  const float* W1   = (const float*)d_in[12];
  const float* B1   = (const float*)d_in[13];
  const float* W2   = (const float*)d_in[14];
  const float* B2   = (const float*)d_in[15];

  float* ws = (float*)d_ws;
  const size_t SZ = (size_t)RR * DM;          // 4 Mi floats
  float* bufA = ws;                           // X (layer input / next X)
  float* bufB = bufA + SZ;                    // Xn / Yn
  float* bufC = bufB + SZ;                    // Q  / Y2
  float* bufD = bufC + SZ;                    // K
  float* bufE = bufD + SZ;                    // V
  float* bufF = bufE + SZ;                    // G (gate)
  float* bufG = bufF + SZ;                    // Yh / GY (in place)
  float* bufH = bufG + SZ;                    // F1 (RR x FFN)
  float* tb   = bufH + (size_t)RR * FFN_;
  float* sq = tb;
  float* cq = sq + (size_t)SS * HDD;
  float* sk = cq + (size_t)SS * HDD;
  float* ck = sk + (size_t)SS * HDD;
  float* lngp = ck + (size_t)SS * HDD;

  init_tables_k<<<SS, HDD, 0, stream>>>(sq, cq, sk, ck, lngp);

  const dim3 g1(16, 32);   // N=1024 GEMMs
  for (int i = 0; i < LN_; ++i) {
    const float* Xin = (i == 0) ? X0 : bufA;
    layernorm_k<<<RR, 256, 0, stream>>>(Xin, ln1w + i * DM, ln1b + i * DM, bufB);
    gemm_k<1><<<g1, 256, 0, stream>>>(bufB, WQ + (size_t)i * HH * DM * HDD, bufC,
                                      nullptr, nullptr, sq, cq, DM, DM);
    gemm_k<2><<<g1, 256, 0, stream>>>(bufB, WK + (size_t)i * HH * DM * HDD, bufD,
                                      nullptr, nullptr, sk, ck, DM, DM);
    gemm_k<0><<<g1, 256, 0, stream>>>(bufB, WV + (size_t)i * HH * DM * HDD, bufE,
                                      nullptr, nullptr, nullptr, nullptr, DM, DM);
    gemm_k<3><<<g1, 256, 0, stream>>>(bufB, WG + (size_t)i * DM * DM, bufF,
                                      nullptr, nullptr, nullptr, nullptr, DM, DM);
    attn_k<<<dim3(32, HH, BB), 256, 0, stream>>>(bufC, bufD, bufE, lngp, bufG);
    gn_gate_k<<<RR * HH / 4, 256, 0, stream>>>(bufG, gnw + i * DM, gnb + i * DM, bufF);
    gemm_k<5><<<g1, 256, 0, stream>>>(bufG, WO + (size_t)i * DM * DM, bufC,
                                      nullptr, Xin, nullptr, nullptr, DM, DM);
    layernorm_k<<<RR, 256, 0, stream>>>(bufC, ln2w + i * DM, ln2b + i * DM, bufB);
    gemm_k<4><<<dim3(64, 32), 256, 0, stream>>>(bufB, W1 + (size_t)i * DM * FFN_, bufH,
                                                B1 + (size_t)i * FFN_, nullptr,
                                                nullptr, nullptr, FFN_, DM);
    float* Xout = (i == LN_ - 1) ? (float*)d_out : bufA;
    gemm_k<6><<<g1, 256, 0, stream>>>(bufH, W2 + (size_t)i * FFN_ * DM, Xout,
                                      B2 + (size_t)i * DM, bufC, nullptr, nullptr,
                                      DM, FFN_);
  }
}

// Round 2
// 3080.920 us; speedup vs baseline: 1.6228x; 1.6228x over previous
//
#include <hip/hip_runtime.h>
#include <cstdint>
#include <cstddef>

#define LN_ 2
#define HH 8
#define DM 1024
#define FFN_ 4096
#define HDD 128
#define SS 2048
#define BB 2
#define RR (BB*SS)   // 4096 rows

typedef __bf16 bf16x8 __attribute__((ext_vector_type(8)));
typedef __bf16 bf16x4 __attribute__((ext_vector_type(4)));
typedef __bf16 bf16x2 __attribute__((ext_vector_type(2)));
typedef float  f32x4  __attribute__((ext_vector_type(4)));

__device__ __forceinline__ float silu_f(float x) { return x / (1.0f + expf(-x)); }

__device__ __forceinline__ float dot4acc(float4 a, float4 b, float acc) {
  return fmaf(a.w, b.w, fmaf(a.z, b.z, fmaf(a.y, b.y, fmaf(a.x, b.x, acc))));
}
__device__ __forceinline__ float4 fma4(float s, float4 v, float4 a) {
  a.x = fmaf(s, v.x, a.x); a.y = fmaf(s, v.y, a.y);
  a.z = fmaf(s, v.z, a.z); a.w = fmaf(s, v.w, a.w);
  return a;
}

// async global->LDS, 16B per lane; LDS dest = wave-uniform base + lane*16
__device__ __forceinline__ void glds16(const void* g, void* l) {
  __builtin_amdgcn_global_load_lds(
      (const __attribute__((address_space(1))) unsigned int*)g,
      (__attribute__((address_space(3))) unsigned int*)l, 16, 0, 0);
}

// Swizzled-tile addressing: operand arrays are tiled [128 rows][64 k] bf16
// (16 KiB/tile, tiles row-of-tiles major). Within tile:
//   byte = row*128 + (kbyte ^ ((row&7)<<4))
// Producers write this layout; GEMM global_load_lds copies it linearly; reads
// use the same XOR -> both-sides-consistent (guide §21).

// ---------------- xPos tables + decay log-gammas (fp64, matches numpy) ------
__global__ void init_tables_k(float* __restrict__ sq, float* __restrict__ cq,
                              float* __restrict__ sk, float* __restrict__ ck,
                              float* __restrict__ lng) {
  int s = blockIdx.x, k = threadIdx.x;
  int j = k >> 1;
  double sv    = (2.0 * j + 0.4 * HDD) / (1.4 * HDD);
  double p     = (double)s / 512.0;
  double scale = pow(sv, p);
  double invf  = pow(10000.0, -((double)j) / 64.0);
  double ang   = (double)s * invf;
  double sn = sin(ang), cs = cos(ang);
  size_t idx = (size_t)s * HDD + k;
  sq[idx] = (float)(sn * scale);
  cq[idx] = (float)(cs * scale);
  sk[idx] = (float)(sn / scale);
  ck[idx] = (float)(cs / scale);
  if (s == 0 && k < HH) {
    double a0 = log(1.0 / 32.0), a1 = log(1.0 / 512.0);
    double x = a0 + (a1 - a0) * ((double)k / 7.0);
    lng[k] = (float)log(1.0 - exp(x));
  }
}

// ---------------- LayerNorm -> packed hi/lo swizzled A-operand --------------
__global__ __launch_bounds__(256) void ln_pack_k(
    const float* __restrict__ X, const float* __restrict__ w,
    const float* __restrict__ b, char* __restrict__ ph, char* __restrict__ pl) {
  const int row = blockIdx.x, tid = threadIdx.x;
  const float* x = X + (size_t)row * DM;
  float4 v = *(const float4*)(x + tid * 4);
  float s = v.x + v.y + v.z + v.w;
  float q = v.x * v.x + v.y * v.y + v.z * v.z + v.w * v.w;
#pragma unroll
  for (int o = 32; o > 0; o >>= 1) { s += __shfl_xor(s, o); q += __shfl_xor(q, o); }
  __shared__ float ss[4], qq[4];
  if ((tid & 63) == 0) { ss[tid >> 6] = s; qq[tid >> 6] = q; }
  __syncthreads();
  float S  = ss[0] + ss[1] + ss[2] + ss[3];
  float Qs = qq[0] + qq[1] + qq[2] + qq[3];
  float mu  = S * (1.0f / DM);
  float var = Qs * (1.0f / DM) - mu * mu;
  float rs  = 1.0f / sqrtf(var + 1e-5f);
  float4 wv = *(const float4*)(w + tid * 4);
  float4 bv = *(const float4*)(b + tid * 4);
  float y[4];
  y[0] = (v.x - mu) * rs * wv.x + bv.x;
  y[1] = (v.y - mu) * rs * wv.y + bv.y;
  y[2] = (v.z - mu) * rs * wv.z + bv.z;
  y[3] = (v.w - mu) * rs * wv.w + bv.w;
  bf16x4 hv, lv;
#pragma unroll
  for (int r = 0; r < 4; ++r) {
    __bf16 h = (__bf16)y[r];
    hv[r] = h;
    lv[r] = (__bf16)(y[r] - (float)h);
  }
  size_t tb = ((size_t)(row >> 7) * (DM / 64) + (tid >> 4)) * 16384;
  int off = (row & 127) * 128 + (((tid & 15) * 8) ^ ((row & 7) << 4));
  *(bf16x4*)(ph + tb + off) = hv;
  *(bf16x4*)(pl + tb + off) = lv;
}

// ---------------- Weight pack: fp32 [K][N] -> transposed swizzled hi/lo -----
__global__ __launch_bounds__(256) void packw_k(
    const float* __restrict__ W, char* __restrict__ dh, char* __restrict__ dl,
    int N, int qkv) {
  const int tn = blockIdx.x, tk = blockIdx.y, nkt = gridDim.y;
  __shared__ float L[64][132];
  const int k0 = tk * 64;
  const size_t srcbase = qkv ? ((size_t)tn * 131072 + (size_t)k0 * 128)
                             : ((size_t)k0 * N + (size_t)tn * 128);
  const int rstr = qkv ? 128 : N;
#pragma unroll
  for (int it = 0; it < 8; ++it) {
    int q = threadIdx.x + it * 256;      // 2048 float4s = 64x128 fp32
    int kk = q >> 5, c4 = (q & 31) * 4;
    float4 v = *(const float4*)(W + srcbase + (size_t)kk * rstr + c4);
    *(float4*)&L[kk][c4] = v;
  }
  __syncthreads();
  const size_t tb = ((size_t)tn * nkt + tk) * 16384;
#pragma unroll
  for (int it = 0; it < 4; ++it) {
    int o = threadIdx.x + it * 256;      // 1024 outputs: (n, k8)
    int n = o >> 3, k8 = o & 7;
    bf16x8 hv, lv;
#pragma unroll
    for (int j = 0; j < 8; ++j) {
      float x = L[k8 * 8 + j][n];
      __bf16 h = (__bf16)x;
      hv[j] = h;
      lv[j] = (__bf16)(x - (float)h);
    }
    int off = n * 128 + ((k8 * 16) ^ ((n & 7) << 4));
    *(bf16x8*)(dh + tb + off) = hv;
    *(bf16x8*)(dl + tb + off) = lv;
  }
}

// ---------------- Split-bf16 MFMA GEMM: C[m][n] = A[m][:]. W[:][n] ----------
// Operands: packed A (activations) and Bt (weights transposed), both in the
// swizzled-tile layout, hi+lo. D computed transposed via weights-as-A-operand
// so each lane's 4 acc elems are consecutive n.
// MODE 0: -> C[b][h][s][k] (QKV)        MODE 1: silu -> row-major (gate)
// MODE 2: + resid -> row-major (WO)     MODE 3: silu(+bias) -> packed (FFN1)
// MODE 4: + bias + resid -> row-major (FFN2)
template <int MODE>
__global__ __launch_bounds__(256, 1) void mgemm_k(
    const char* __restrict__ pAh, const char* __restrict__ pAl,
    const char* __restrict__ pBh, const char* __restrict__ pBl,
    float* __restrict__ C, const float* __restrict__ bias,
    const float* __restrict__ resid, char* __restrict__ outH,
    char* __restrict__ outL, int M, int N, int K) {
  __shared__ char lds[2][4][16384];  // [buf][Ah,Al,Bh,Bl] = 128 KiB
  const int tid = threadIdx.x, lane = tid & 63, w = tid >> 6;
  const int wm = w & 1, wn = w >> 1;
  const int bx = blockIdx.x, by = blockIdx.y;
  const int nkt = K >> 6;
  const size_t tileA0 = (size_t)by * nkt * 16384;
  const size_t tileB0 = (size_t)bx * nkt * 16384;
  const int swz = (lane & 7) << 4;
  const int l15 = lane & 15, l4 = lane >> 4;

  f32x4 acc[4][4];
#pragma unroll
  for (int i = 0; i < 4; ++i)
#pragma unroll
    for (int j = 0; j < 4; ++j) acc[i][j] = (f32x4){0.f, 0.f, 0.f, 0.f};

  auto stage = [&](int buf, int t) {
    const size_t oA = tileA0 + (size_t)t * 16384;
    const size_t oB = tileB0 + (size_t)t * 16384;
#pragma unroll
    for (int c = 0; c < 4; ++c) {
      const size_t go = (size_t)c * 4096 + w * 1024 + lane * 16;
      const int lo = c * 4096 + w * 1024;
      glds16(pAh + oA + go, &lds[buf][0][lo]);
      glds16(pAl + oA + go, &lds[buf][1][lo]);
      glds16(pBh + oB + go, &lds[buf][2][lo]);
      glds16(pBl + oB + go, &lds[buf][3][lo]);
    }
  };

  auto comp = [&](int buf) {
#pragma unroll
    for (int ks = 0; ks < 2; ++ks) {
      const int kb = ks * 64 + l4 * 16;
      bf16x8 amh[4], aml[4], anh[4], anl[4];
#pragma unroll
      for (int f = 0; f < 4; ++f) {
        const int rm = wm * 64 + f * 16 + l15;
        const int ra = rm * 128 + (kb ^ swz);
        amh[f] = *(const bf16x8*)&lds[buf][0][ra];
        aml[f] = *(const bf16x8*)&lds[buf][1][ra];
        const int rn = wn * 64 + f * 16 + l15;
        const int rb = rn * 128 + (kb ^ swz);
        anh[f] = *(const bf16x8*)&lds[buf][2][rb];
        anl[f] = *(const bf16x8*)&lds[buf][3][rb];
      }
#pragma unroll
      for (int nf = 0; nf < 4; ++nf)
#pragma unroll
        for (int mf = 0; mf < 4; ++mf) {
          acc[nf][mf] = __builtin_amdgcn_mfma_f32_16x16x32_bf16(
              anh[nf], amh[mf], acc[nf][mf], 0, 0, 0);
          acc[nf][mf] = __builtin_amdgcn_mfma_f32_16x16x32_bf16(
              anh[nf], aml[mf], acc[nf][mf], 0, 0, 0);
          acc[nf][mf] = __builtin_amdgcn_mfma_f32_16x16x32_bf16(
              anl[nf], amh[mf], acc[nf][mf], 0, 0, 0);
        }
    }
  };

  stage(0, 0);
  __syncthreads();
  int buf = 0;
  for (int t = 0; t < nkt - 1; ++t) {
    stage(buf ^ 1, t + 1);   // issue next-tile loads: latency hides under MFMA
    comp(buf);
    __syncthreads();         // vmcnt(0)+lgkmcnt drain: loads had compute-time
    buf ^= 1;
  }
  comp(buf);

  const int mBase = by * 128 + wm * 64 + l15;
  const int nBase = bx * 128 + wn * 64 + l4 * 4;
#pragma unroll
  for (int nf = 0; nf < 4; ++nf)
#pragma unroll
    for (int mf = 0; mf < 4; ++mf) {
      const int m = mBase + mf * 16;
      const int n = nBase + nf * 16;
      f32x4 v = acc[nf][mf];
      if (MODE == 0) {
        *(f32x4*)(C + (((size_t)(m >> 11) * HH + (n >> 7)) * SS + (m & (SS - 1)))
                          * HDD + (n & (HDD - 1))) = v;
      } else if (MODE == 1) {
#pragma unroll
        for (int r = 0; r < 4; ++r) v[r] = silu_f(v[r]);
        *(f32x4*)(C + (size_t)m * N + n) = v;
      } else if (MODE == 2) {
        f32x4 rz = *(const f32x4*)(resid + (size_t)m * N + n);
        v += rz;
        *(f32x4*)(C + (size_t)m * N + n) = v;
      } else if (MODE == 3) {
        f32x4 bz = *(const f32x4*)(bias + n);
        bf16x4 hv, lv;
#pragma unroll
        for (int r = 0; r < 4; ++r) {
          float y = silu_f(v[r] + bz[r]);
          __bf16 h = (__bf16)y;
          hv[r] = h;
          lv[r] = (__bf16)(y - (float)h);
        }
        size_t tb = ((size_t)(m >> 7) * (N >> 6) + (n >> 6)) * 16384;
        int off = (m & 127) * 128 + (((n & 63) * 2) ^ ((m & 7) << 4));
        *(bf16x4*)(outH + tb + off) = hv;
        *(bf16x4*)(outL + tb + off) = lv;
      } else {  // MODE 4
        f32x4 bz = *(const f32x4*)(bias + n);
        f32x4 rz = *(const f32x4*)(resid + (size_t)m * N + n);
        v += bz + rz;
        *(f32x4*)(C + (size_t)m * N + n) = v;
      }
    }
}

// ---------------- xPos rotary in-place on [B][H][S][128] --------------------
__global__ __launch_bounds__(256) void rope_k(
    float* __restrict__ T, const float* __restrict__ sn, const float* __restrict__ cs) {
  size_t idx = (size_t)blockIdx.x * 256 + threadIdx.x;  // float4 index, 1M total
  int k4 = (idx & 31) * 4;
  int s  = (int)((idx >> 5) & (SS - 1));
  float4 v = ((float4*)T)[idx];
  float4 snv = *(const float4*)(sn + (size_t)s * HDD + k4);
  float4 csv = *(const float4*)(cs + (size_t)s * HDD + k4);
  float4 o;
  o.x = v.x * csv.x - v.y * snv.x;
  o.y = v.y * csv.y + v.x * snv.y;
  o.z = v.z * csv.z - v.w * snv.z;
  o.w = v.w * csv.w + v.z * snv.w;
  ((float4*)T)[idx] = o;
}

// ---------------- Retention (decay-masked attention), fp32 (unchanged) ------
__global__ __launch_bounds__(256) void attn_k(
    const float* __restrict__ Q, const float* __restrict__ Kp,
    const float* __restrict__ V, const float* __restrict__ lng,
    float* __restrict__ Y) {
  const int qt = 31 - blockIdx.x;
  const int h  = blockIdx.y, bI = blockIdx.z;
  const float lg = lng[h];
  const size_t base = ((size_t)bI * HH + h) * SS * HDD;
  __shared__ float Qs[64][132];
  __shared__ float KVs[32][136];
  __shared__ float Sls[64][36];
  const int tid = threadIdx.x;
  const float* Qp = Q + base + (size_t)qt * 64 * HDD;
#pragma unroll
  for (int it = 0; it < 8; ++it) {
    int idx = tid + it * 256;
    int r = idx >> 5, c4 = (idx & 31) << 2;
    *(float4*)&Qs[r][c4] = *(const float4*)(Qp + (size_t)r * HDD + c4);
  }
  float4 acc[4][2] = {};
  const int rg = tid >> 4, cg = tid & 15;
  const int nkt = 2 * qt + 2;
  for (int kt = 0; kt < nkt; ++kt) {
    const int m0 = kt * 32;
    __syncthreads();
#pragma unroll
    for (int it = 0; it < 4; ++it) {
      int idx = tid + it * 256;
      int r = idx >> 5, c4 = (idx & 31) << 2;
      *(float4*)&KVs[r][c4] = *(const float4*)(Kp + base + (size_t)(m0 + r) * HDD + c4);
    }
    __syncthreads();
    float sc[4][2] = {};
#pragma unroll
    for (int d4 = 0; d4 < 32; ++d4) {
      int d = d4 * 4;
      float4 k0 = *(const float4*)&KVs[cg * 2 + 0][d];
      float4 k1 = *(const float4*)&KVs[cg * 2 + 1][d];
      float4 q0 = *(const float4*)&Qs[rg * 4 + 0][d];
      float4 q1 = *(const float4*)&Qs[rg * 4 + 1][d];
      float4 q2 = *(const float4*)&Qs[rg * 4 + 2][d];
      float4 q3 = *(const float4*)&Qs[rg * 4 + 3][d];
      sc[0][0] = dot4acc(q0, k0, sc[0][0]); sc[0][1] = dot4acc(q0, k1, sc[0][1]);
      sc[1][0] = dot4acc(q1, k0, sc[1][0]); sc[1][1] = dot4acc(q1, k1, sc[1][1]);
      sc[2][0] = dot4acc(q2, k0, sc[2][0]); sc[2][1] = dot4acc(q2, k1, sc[2][1]);
      sc[3][0] = dot4acc(q3, k0, sc[3][0]); sc[3][1] = dot4acc(q3, k1, sc[3][1]);
    }
    const int nb = qt * 64 + rg * 4;
#pragma unroll
    for (int i = 0; i < 4; ++i)
#pragma unroll
      for (int j = 0; j < 2; ++j) {
        int n = nb + i, m = m0 + cg * 2 + j;
        float dmul = (n >= m) ? expf((float)(n - m) * lg) : 0.0f;
        sc[i][j] *= dmul;
      }
    __syncthreads();
#pragma unroll
    for (int i = 0; i < 4; ++i) {
      Sls[rg * 4 + i][cg * 2 + 0] = sc[i][0];
      Sls[rg * 4 + i][cg * 2 + 1] = sc[i][1];
    }
#pragma unroll
    for (int it = 0; it < 4; ++it) {
      int idx = tid + it * 256;
      int r = idx >> 5, c4 = (idx & 31) << 2;
      *(float4*)&KVs[r][c4] = *(const float4*)(V + base + (size_t)(m0 + r) * HDD + c4);
    }
    __syncthreads();
#pragma unroll 8
    for (int j = 0; j < 32; ++j) {
      float s0 = Sls[rg * 4 + 0][j];
      float s1 = Sls[rg * 4 + 1][j];
      float s2 = Sls[rg * 4 + 2][j];
      float s3 = Sls[rg * 4 + 3][j];
      float4 v0 = *(const float4*)&KVs[j][cg * 8];
      float4 v1 = *(const float4*)&KVs[j][cg * 8 + 4];
      acc[0][0] = fma4(s0, v0, acc[0][0]); acc[0][1] = fma4(s0, v1, acc[0][1]);
      acc[1][0] = fma4(s1, v0, acc[1][0]); acc[1][1] = fma4(s1, v1, acc[1][1]);
      acc[2][0] = fma4(s2, v0, acc[2][0]); acc[2][1] = fma4(s2, v1, acc[2][1]);
      acc[3][0] = fma4(s3, v0, acc[3][0]); acc[3][1] = fma4(s3, v1, acc[3][1]);
    }
  }
#pragma unroll
  for (int i = 0; i < 4; ++i) {
    size_t row = (size_t)bI * SS + qt * 64 + rg * 4 + i;
    float* dst = Y + row * DM + h * HDD + cg * 8;
    *(float4*)dst       = acc[i][0];
    *(float4*)(dst + 4) = acc[i][1];
  }
}

// ---------------- GroupNorm * gate -> packed hi/lo swizzled A-operand -------
__global__ __launch_bounds__(256) void gn_gate_k(
    const float* __restrict__ Y, const float* __restrict__ w,
    const float* __restrict__ b, const float* __restrict__ G,
    char* __restrict__ ph, char* __restrict__ pl) {
  int g    = blockIdx.x * 4 + (threadIdx.x >> 6);
  int lane = threadIdx.x & 63;
  float2 v = *(const float2*)(Y + (size_t)g * HDD + lane * 2);
  float s = v.x + v.y, q = v.x * v.x + v.y * v.y;
#pragma unroll
  for (int o = 32; o > 0; o >>= 1) { s += __shfl_xor(s, o); q += __shfl_xor(q, o); }
  float mu  = s * (1.0f / HDD);
  float var = q * (1.0f / HDD) - mu * mu;
  float rs  = 1.0f / sqrtf(var + 1e-5f);
  int m   = g >> 3;
  int col = (g & 7) * HDD + lane * 2;
  float2 wv = *(const float2*)(w + col);
  float2 bv = *(const float2*)(b + col);
  float2 gv = *(const float2*)(G + (size_t)g * HDD + lane * 2);
  float ox = ((v.x - mu) * rs * wv.x + bv.x) * gv.x;
  float oy = ((v.y - mu) * rs * wv.y + bv.y) * gv.y;
  __bf16 hx = (__bf16)ox, hy = (__bf16)oy;
  bf16x2 hv, lv;
  hv[0] = hx; hv[1] = hy;
  lv[0] = (__bf16)(ox - (float)hx); lv[1] = (__bf16)(oy - (float)hy);
  size_t tb = ((size_t)(m >> 7) * (DM / 64) + (col >> 6)) * 16384;
  int off = (m & 127) * 128 + (((col & 63) * 2) ^ ((m & 7) << 4));
  *(bf16x2*)(ph + tb + off) = hv;
  *(bf16x2*)(pl + tb + off) = lv;
}

// ---------------- driver -----------------------------------------------------
extern "C" void kernel_launch(void* const* d_in, const int* in_sizes, int n_in,
                              void* d_out, int out_size, void* d_ws, size_t ws_size,
                              hipStream_t stream) {
  (void)in_sizes; (void)n_in; (void)out_size; (void)ws_size;
  const float* X0   = (const float*)d_in[0];
  const float* ln1w = (const float*)d_in[1];
  const float* ln1b = (const float*)d_in[2];
  const float* ln2w = (const float*)d_in[3];
  const float* ln2b = (const float*)d_in[4];
  const float* WQ   = (const float*)d_in[5];
  const float* WK   = (const float*)d_in[6];
  const float* WV   = (const float*)d_in[7];
  const float* gnw  = (const float*)d_in[8];
  const float* gnb  = (const float*)d_in[9];
  const float* WG   = (const float*)d_in[10];
  const float* WO   = (const float*)d_in[11];
  const float* W1   = (const float*)d_in[12];
  const float* B1   = (const float*)d_in[13];
  const float* W2   = (const float*)d_in[14];
  const float* B2   = (const float*)d_in[15];

  float* ws = (float*)d_ws;
  const size_t SZ = (size_t)RR * DM;          // 4 Mi floats
  float* bufA = ws + 0 * SZ;                  // X carry
  float* bufB = ws + 1 * SZ;                  // Y (WO out, FFN resid)
  float* bufC = ws + 2 * SZ;                  // Q
  float* bufD = ws + 3 * SZ;                  // K
  float* bufE = ws + 4 * SZ;                  // V
  float* bufF = ws + 5 * SZ;                  // gate (silu)
  float* bufG = ws + 6 * SZ;                  // Yh
  float* sq   = ws + 28 * 1048576;
  float* cq   = sq + SS * HDD;
  float* sk   = cq + SS * HDD;
  float* ck   = sk + SS * HDD;
  float* lngp = ws + 29 * 1048576;
  char*  pb   = (char*)(ws + (size_t)30 * 1048576);
  char* pXh = pb;                             // 8 MB (4M elems)
  char* pXl = pb + ((size_t)8  << 20);
  char* pFh = pb + ((size_t)16 << 20);        // 32 MB (16M elems)
  char* pFl = pb + ((size_t)48 << 20);
  char* pWh = pb + ((size_t)80 << 20);        // 26 MB (13M elems)
  char* pWl = pb + ((size_t)106 << 20);
  // weight region byte offsets (elems*2B)
  const size_t oWQ = 0, oWK = (size_t)2 << 20, oWV = (size_t)4 << 20,
               oWG = (size_t)6 << 20, oWO = (size_t)8 << 20,
               oW1 = (size_t)10 << 20, oW2 = (size_t)18 << 20;

  init_tables_k<<<SS, HDD, 0, stream>>>(sq, cq, sk, ck, lngp);

  const dim3 g1(8, 32);    // N=1024 GEMMs
  const dim3 gF1(32, 32);  // N=4096
  for (int i = 0; i < LN_; ++i) {
    const float* Xin = (i == 0) ? X0 : bufA;
    // pack layer weights (transpose + hi/lo split + swizzle)
    packw_k<<<dim3(8, 16), 256, 0, stream>>>(WQ + (size_t)i * 1048576, pWh + oWQ, pWl + oWQ, 1024, 1);
    packw_k<<<dim3(8, 16), 256, 0, stream>>>(WK + (size_t)i * 1048576, pWh + oWK, pWl + oWK, 1024, 1);
    packw_k<<<dim3(8, 16), 256, 0, stream>>>(WV + (size_t)i * 1048576, pWh + oWV, pWl + oWV, 1024, 1);
    packw_k<<<dim3(8, 16), 256, 0, stream>>>(WG + (size_t)i * 1048576, pWh + oWG, pWl + oWG, 1024, 0);
    packw_k<<<dim3(8, 16), 256, 0, stream>>>(WO + (size_t)i * 1048576, pWh + oWO, pWl + oWO, 1024, 0);
    packw_k<<<dim3(32, 16), 256, 0, stream>>>(W1 + (size_t)i * 4194304, pWh + oW1, pWl + oW1, 4096, 0);
    packw_k<<<dim3(8, 64), 256, 0, stream>>>(W2 + (size_t)i * 4194304, pWh + oW2, pWl + oW2, 1024, 0);

    ln_pack_k<<<RR, 256, 0, stream>>>(Xin, ln1w + i * DM, ln1b + i * DM, pXh, pXl);
    mgemm_k<0><<<g1, 256, 0, stream>>>(pXh, pXl, pWh + oWQ, pWl + oWQ, bufC,
                                       nullptr, nullptr, nullptr, nullptr, RR, DM, DM);
    mgemm_k<0><<<g1, 256, 0, stream>>>(pXh, pXl, pWh + oWK, pWl + oWK, bufD,
                                       nullptr, nullptr, nullptr, nullptr, RR, DM, DM);
    mgemm_k<0><<<g1, 256, 0, stream>>>(pXh, pXl, pWh + oWV, pWl + oWV, bufE,
                                       nullptr, nullptr, nullptr, nullptr, RR, DM, DM);
    mgemm_k<1><<<g1, 256, 0, stream>>>(pXh, pXl, pWh + oWG, pWl + oWG, bufF,
                                       nullptr, nullptr, nullptr, nullptr, RR, DM, DM);
    rope_k<<<4096, 256, 0, stream>>>(bufC, sq, cq);
    rope_k<<<4096, 256, 0, stream>>>(bufD, sk, ck);
    attn_k<<<dim3(32, HH, BB), 256, 0, stream>>>(bufC, bufD, bufE, lngp, bufG);
    gn_gate_k<<<RR * HH / 4, 256, 0, stream>>>(bufG, gnw + i * DM, gnb + i * DM,
                                               bufF, pXh, pXl);
    mgemm_k<2><<<g1, 256, 0, stream>>>(pXh, pXl, pWh + oWO, pWl + oWO, bufB,
                                       nullptr, Xin, nullptr, nullptr, RR, DM, DM);
    ln_pack_k<<<RR, 256, 0, stream>>>(bufB, ln2w + i * DM, ln2b + i * DM, pXh, pXl);
    mgemm_k<3><<<gF1, 256, 0, stream>>>(pXh, pXl, pWh + oW1, pWl + oW1, nullptr,
                                        B1 + (size_t)i * FFN_, nullptr, pFh, pFl,
                                        RR, FFN_, DM);
    float* Xout = (i == LN_ - 1) ? (float*)d_out : bufA;
    mgemm_k<4><<<g1, 256, 0, stream>>>(pFh, pFl, pWh + oW2, pWl + oW2, Xout,
                                       B2 + (size_t)i * DM, bufB, nullptr, nullptr,
                                       RR, DM, FFN_);
  }
}

// Round 3
// 1301.668 us; speedup vs baseline: 3.8411x; 2.3669x over previous
//
#include <hip/hip_runtime.h>
#include <cstdint>
#include <cstddef>

#define LN_ 2
#define HH 8
#define DM 1024
#define FFN_ 4096
#define HDD 128
#define SS 2048
#define BB 2
#define RR (BB*SS)   // 4096 rows

typedef __bf16 bf16x8 __attribute__((ext_vector_type(8)));
typedef __bf16 bf16x4 __attribute__((ext_vector_type(4)));
typedef __bf16 bf16x2 __attribute__((ext_vector_type(2)));
typedef float  f32x4  __attribute__((ext_vector_type(4)));

__device__ __forceinline__ float silu_f(float x) { return x / (1.0f + expf(-x)); }

// async global->LDS, 16B per lane; LDS dest = wave-uniform base + lane*16
__device__ __forceinline__ void glds16(const void* g, void* l) {
  __builtin_amdgcn_global_load_lds(
      (const __attribute__((address_space(1))) unsigned int*)g,
      (__attribute__((address_space(3))) unsigned int*)l, 16, 0, 0);
}

// Packed operand tiles: [128 rows][64 k] bf16 = 16 KiB, within-tile byte =
// row*128 + ((2*k) ^ ((row&7)<<4)). Producers write this; GEMM/attn stage it
// linearly via glds16 and read with the same XOR (both-sides, guide §21).

// ---------------- xPos tables + decay log2-gammas (fp64, matches numpy) -----
__global__ void init_tables_k(float* __restrict__ sq, float* __restrict__ cq,
                              float* __restrict__ sk, float* __restrict__ ck,
                              float* __restrict__ lg2g) {
  int s = blockIdx.x, k = threadIdx.x;
  int j = k >> 1;
  double sv    = (2.0 * j + 0.4 * HDD) / (1.4 * HDD);
  double p     = (double)s / 512.0;
  double scale = pow(sv, p);
  double invf  = pow(10000.0, -((double)j) / 64.0);
  double ang   = (double)s * invf;
  double sn = sin(ang), cs = cos(ang);
  size_t idx = (size_t)s * HDD + k;
  sq[idx] = (float)(sn * scale);
  cq[idx] = (float)(cs * scale);
  sk[idx] = (float)(sn / scale);
  ck[idx] = (float)(cs / scale);
  if (s == 0 && k < HH) {
    double a0 = log(1.0 / 32.0), a1 = log(1.0 / 512.0);
    double x = a0 + (a1 - a0) * ((double)k / 7.0);
    lg2g[k] = (float)(log(1.0 - exp(x)) / log(2.0));
  }
}

// ---------------- LayerNorm -> packed hi/lo swizzled A-operand --------------
__global__ __launch_bounds__(256) void ln_pack_k(
    const float* __restrict__ X, const float* __restrict__ w,
    const float* __restrict__ b, char* __restrict__ ph, char* __restrict__ pl) {
  const int row = blockIdx.x, tid = threadIdx.x;
  const float* x = X + (size_t)row * DM;
  float4 v = *(const float4*)(x + tid * 4);
  float s = v.x + v.y + v.z + v.w;
  float q = v.x * v.x + v.y * v.y + v.z * v.z + v.w * v.w;
#pragma unroll
  for (int o = 32; o > 0; o >>= 1) { s += __shfl_xor(s, o); q += __shfl_xor(q, o); }
  __shared__ float ss[4], qq[4];
  if ((tid & 63) == 0) { ss[tid >> 6] = s; qq[tid >> 6] = q; }
  __syncthreads();
  float S  = ss[0] + ss[1] + ss[2] + ss[3];
  float Qs = qq[0] + qq[1] + qq[2] + qq[3];
  float mu  = S * (1.0f / DM);
  float var = Qs * (1.0f / DM) - mu * mu;
  float rs  = 1.0f / sqrtf(var + 1e-5f);
  float4 wv = *(const float4*)(w + tid * 4);
  float4 bv = *(const float4*)(b + tid * 4);
  float y[4];
  y[0] = (v.x - mu) * rs * wv.x + bv.x;
  y[1] = (v.y - mu) * rs * wv.y + bv.y;
  y[2] = (v.z - mu) * rs * wv.z + bv.z;
  y[3] = (v.w - mu) * rs * wv.w + bv.w;
  bf16x4 hv, lv;
#pragma unroll
  for (int r = 0; r < 4; ++r) {
    __bf16 h = (__bf16)y[r];
    hv[r] = h;
    lv[r] = (__bf16)(y[r] - (float)h);
  }
  size_t tb = ((size_t)(row >> 7) * (DM / 64) + (tid >> 4)) * 16384;
  int off = (row & 127) * 128 + (((tid & 15) * 8) ^ ((row & 7) << 4));
  *(bf16x4*)(ph + tb + off) = hv;
  *(bf16x4*)(pl + tb + off) = lv;
}

// ---------------- Weight pack: fp32 [K][N] -> transposed swizzled hi/lo -----
__global__ __launch_bounds__(256) void packw_k(
    const float* __restrict__ W, char* __restrict__ dh, char* __restrict__ dl,
    int N, int qkv) {
  const int tn = blockIdx.x, tk = blockIdx.y, nkt = gridDim.y;
  __shared__ float L[64][132];
  const int k0 = tk * 64;
  const size_t srcbase = qkv ? ((size_t)tn * 131072 + (size_t)k0 * 128)
                             : ((size_t)k0 * N + (size_t)tn * 128);
  const int rstr = qkv ? 128 : N;
#pragma unroll
  for (int it = 0; it < 8; ++it) {
    int q = threadIdx.x + it * 256;
    int kk = q >> 5, c4 = (q & 31) * 4;
    float4 v = *(const float4*)(W + srcbase + (size_t)kk * rstr + c4);
    *(float4*)&L[kk][c4] = v;
  }
  __syncthreads();
  const size_t tb = ((size_t)tn * nkt + tk) * 16384;
#pragma unroll
  for (int it = 0; it < 4; ++it) {
    int o = threadIdx.x + it * 256;
    int n = o >> 3, k8 = o & 7;
    bf16x8 hv, lv;
#pragma unroll
    for (int j = 0; j < 8; ++j) {
      float x = L[k8 * 8 + j][n];
      __bf16 h = (__bf16)x;
      hv[j] = h;
      lv[j] = (__bf16)(x - (float)h);
    }
    int off = n * 128 + ((k8 * 16) ^ ((n & 7) << 4));
    *(bf16x8*)(dh + tb + off) = hv;
    *(bf16x8*)(dl + tb + off) = lv;
  }
}

// ---------------- V fp32 [b][h][s][d] -> V^T packed tiles (rows=d, k=s) -----
__global__ __launch_bounds__(256) void vtpack_k(
    const float* __restrict__ V, char* __restrict__ dh, char* __restrict__ dl) {
  const int st = blockIdx.x, bh = blockIdx.y;
  __shared__ float L[64][132];
  const float* src = V + ((size_t)bh * SS + st * 64) * HDD;
#pragma unroll
  for (int it = 0; it < 8; ++it) {
    int q = threadIdx.x + it * 256;
    int r = q >> 5, c4 = (q & 31) * 4;
    *(float4*)&L[r][c4] = *(const float4*)(src + (size_t)r * HDD + c4);
  }
  __syncthreads();
  const size_t tb = ((size_t)bh * 32 + st) * 16384;
#pragma unroll
  for (int it = 0; it < 4; ++it) {
    int o = threadIdx.x + it * 256;
    int d = o >> 3, s8 = o & 7;
    bf16x8 hv, lv;
#pragma unroll
    for (int j = 0; j < 8; ++j) {
      float x = L[s8 * 8 + j][d];
      __bf16 h = (__bf16)x;
      hv[j] = h;
      lv[j] = (__bf16)(x - (float)h);
    }
    int off = d * 128 + ((s8 * 16) ^ ((d & 7) << 4));
    *(bf16x8*)(dh + tb + off) = hv;
    *(bf16x8*)(dl + tb + off) = lv;
  }
}

// ---------------- Split-bf16 MFMA GEMM ---------------------------------------
// MODE 0: -> C[b][h][s][d] fp32 (V)    MODE 1: silu -> row-major (gate)
// MODE 2: + resid -> row-major (WO)    MODE 3: silu(+bias) -> packed (FFN1)
// MODE 4: + bias + resid (FFN2)        MODE 5: rotary -> packed per-bh (Q/K)
template <int MODE>
__global__ __launch_bounds__(256, 1) void mgemm_k(
    const char* __restrict__ pAh, const char* __restrict__ pAl,
    const char* __restrict__ pBh, const char* __restrict__ pBl,
    float* __restrict__ C, const float* __restrict__ bias,
    const float* __restrict__ resid, char* __restrict__ outH,
    char* __restrict__ outL, const float* __restrict__ tsin,
    const float* __restrict__ tcos, int M, int N, int K) {
  __shared__ char lds[2][4][16384];  // [buf][Ah,Al,Bh,Bl] = 128 KiB
  const int tid = threadIdx.x, lane = tid & 63, w = tid >> 6;
  const int wm = w & 1, wn = w >> 1;
  const int bx = blockIdx.x, by = blockIdx.y;
  const int nkt = K >> 6;
  const size_t tileA0 = (size_t)by * nkt * 16384;
  const size_t tileB0 = (size_t)bx * nkt * 16384;
  const int swz = (lane & 7) << 4;
  const int l15 = lane & 15, l4 = lane >> 4;

  f32x4 acc[4][4];
#pragma unroll
  for (int i = 0; i < 4; ++i)
#pragma unroll
    for (int j = 0; j < 4; ++j) acc[i][j] = (f32x4){0.f, 0.f, 0.f, 0.f};

  auto stage = [&](int buf, int t) {
    const size_t oA = tileA0 + (size_t)t * 16384;
    const size_t oB = tileB0 + (size_t)t * 16384;
#pragma unroll
    for (int c = 0; c < 4; ++c) {
      const size_t go = (size_t)c * 4096 + w * 1024 + lane * 16;
      const int lo = c * 4096 + w * 1024;
      glds16(pAh + oA + go, &lds[buf][0][lo]);
      glds16(pAl + oA + go, &lds[buf][1][lo]);
      glds16(pBh + oB + go, &lds[buf][2][lo]);
      glds16(pBl + oB + go, &lds[buf][3][lo]);
    }
  };

  auto comp = [&](int buf) {
#pragma unroll
    for (int ks = 0; ks < 2; ++ks) {
      const int kb = ks * 64 + l4 * 16;
      bf16x8 amh[4], aml[4], anh[4], anl[4];
#pragma unroll
      for (int f = 0; f < 4; ++f) {
        const int rm = wm * 64 + f * 16 + l15;
        const int ra = rm * 128 + (kb ^ swz);
        amh[f] = *(const bf16x8*)&lds[buf][0][ra];
        aml[f] = *(const bf16x8*)&lds[buf][1][ra];
        const int rn = wn * 64 + f * 16 + l15;
        const int rb = rn * 128 + (kb ^ swz);
        anh[f] = *(const bf16x8*)&lds[buf][2][rb];
        anl[f] = *(const bf16x8*)&lds[buf][3][rb];
      }
#pragma unroll
      for (int nf = 0; nf < 4; ++nf)
#pragma unroll
        for (int mf = 0; mf < 4; ++mf) {
          acc[nf][mf] = __builtin_amdgcn_mfma_f32_16x16x32_bf16(
              anh[nf], amh[mf], acc[nf][mf], 0, 0, 0);
          acc[nf][mf] = __builtin_amdgcn_mfma_f32_16x16x32_bf16(
              anh[nf], aml[mf], acc[nf][mf], 0, 0, 0);
          acc[nf][mf] = __builtin_amdgcn_mfma_f32_16x16x32_bf16(
              anl[nf], amh[mf], acc[nf][mf], 0, 0, 0);
        }
    }
  };

  stage(0, 0);
  __syncthreads();
  int buf = 0;
  for (int t = 0; t < nkt - 1; ++t) {
    stage(buf ^ 1, t + 1);
    comp(buf);
    __syncthreads();
    buf ^= 1;
  }
  comp(buf);

  const int mBase = by * 128 + wm * 64 + l15;
  const int nBase = bx * 128 + wn * 64 + l4 * 4;
#pragma unroll
  for (int nf = 0; nf < 4; ++nf)
#pragma unroll
    for (int mf = 0; mf < 4; ++mf) {
      const int m = mBase + mf * 16;
      const int n = nBase + nf * 16;
      f32x4 v = acc[nf][mf];
      if (MODE == 0) {
        *(f32x4*)(C + (((size_t)(m >> 11) * HH + (n >> 7)) * SS + (m & (SS - 1)))
                          * HDD + (n & (HDD - 1))) = v;
      } else if (MODE == 1) {
#pragma unroll
        for (int r = 0; r < 4; ++r) v[r] = silu_f(v[r]);
        *(f32x4*)(C + (size_t)m * N + n) = v;
      } else if (MODE == 2) {
        f32x4 rz = *(const f32x4*)(resid + (size_t)m * N + n);
        v += rz;
        *(f32x4*)(C + (size_t)m * N + n) = v;
      } else if (MODE == 3) {
        f32x4 bz = *(const f32x4*)(bias + n);
        bf16x4 hv, lv;
#pragma unroll
        for (int r = 0; r < 4; ++r) {
          float y = silu_f(v[r] + bz[r]);
          __bf16 h = (__bf16)y;
          hv[r] = h;
          lv[r] = (__bf16)(y - (float)h);
        }
        size_t tb = ((size_t)(m >> 7) * (N >> 6) + (n >> 6)) * 16384;
        int off = (m & 127) * 128 + (((n & 63) * 2) ^ ((m & 7) << 4));
        *(bf16x4*)(outH + tb + off) = hv;
        *(bf16x4*)(outL + tb + off) = lv;
      } else if (MODE == 4) {
        f32x4 bz = *(const f32x4*)(bias + n);
        f32x4 rz = *(const f32x4*)(resid + (size_t)m * N + n);
        v += bz + rz;
        *(f32x4*)(C + (size_t)m * N + n) = v;
      } else {  // MODE 5: rotary + packed per-(b,h) tiles (rows=s, k=d)
        int s = m & (SS - 1);
        int d = n & (HDD - 1);
        f32x4 sn = *(const f32x4*)(tsin + (size_t)s * HDD + d);
        f32x4 cn = *(const f32x4*)(tcos + (size_t)s * HDD + d);
        float o0 = v[0] * cn[0] - v[1] * sn[0];
        float o1 = v[1] * cn[1] + v[0] * sn[1];
        float o2 = v[2] * cn[2] - v[3] * sn[2];
        float o3 = v[3] * cn[3] + v[2] * sn[3];
        float oo[4] = {o0, o1, o2, o3};
        bf16x4 hv, lv;
#pragma unroll
        for (int r = 0; r < 4; ++r) {
          __bf16 h = (__bf16)oo[r];
          hv[r] = h;
          lv[r] = (__bf16)(oo[r] - (float)h);
        }
        size_t tile = ((size_t)(m >> 11) * HH + (n >> 7)) * 32 + (s >> 7) * 2 + (d >> 6);
        size_t off = tile * 16384 + (s & 127) * 128 + (((d & 63) * 2) ^ ((s & 7) << 4));
        *(bf16x4*)(outH + off) = hv;
        *(bf16x4*)(outL + off) = lv;
      }
    }
}

// ---------------- Retention via split-bf16 MFMA ------------------------------
// grid (32 qt, 16 bh); 256 thr; Q-tile 64 n x 128 d in regs; K/V tiles 64 m.
// LDS 80 KB -> 2 blocks/CU.
__global__ __launch_bounds__(256, 2) void mattn_k(
    const char* __restrict__ pQh, const char* __restrict__ pQl,
    const char* __restrict__ pKh, const char* __restrict__ pKl,
    const char* __restrict__ pVh, const char* __restrict__ pVl,
    const float* __restrict__ lg2g, float* __restrict__ Y) {
  __shared__ char Kls[2][2][8192];   // [dt][hl][64 m rows * 128B]
  __shared__ char Vls[2][16384];     // [hl][128 d rows * 128B]
  __shared__ char Pls[2][8192];      // [hl][64 n rows * 128B]
  const int qt = 31 - blockIdx.x;    // heavy blocks first
  const int bh = blockIdx.y;
  const int tid = threadIdx.x, lane = tid & 63, w = tid >> 6;
  const int wn = w & 1, wq = w >> 1;  // wq = m-half (QK^T) / d-half (PV)
  const int l15 = lane & 15, lg = lane >> 4;
  const float lg2 = lg2g[bh & 7];
  const size_t tb0 = (size_t)bh * 32;  // packed tile base index for this (b,h)
  const int n0 = qt * 64;
  const int nt = qt + 1;

  // Q A-fragments (hi/lo) held in registers for the whole block
  bf16x8 qh[2][4], ql[2][4];
#pragma unroll
  for (int nf = 0; nf < 2; ++nf) {
    int rr = n0 + wn * 32 + nf * 16 + l15;
    size_t rowbase = (tb0 + (size_t)(rr >> 7) * 2) * 16384 + (size_t)(rr & 127) * 128;
    int sw = (rr & 7) << 4;
#pragma unroll
    for (int ks = 0; ks < 4; ++ks) {
      int d = ks * 32 + lg * 8;
      size_t a = rowbase + (size_t)(d >> 6) * 16384 + (((d & 63) * 2) ^ sw);
      qh[nf][ks] = *(const bf16x8*)(pQh + a);
      ql[nf][ks] = *(const bf16x8*)(pQl + a);
    }
  }

  f32x4 yacc[2][4];
#pragma unroll
  for (int i = 0; i < 2; ++i)
#pragma unroll
    for (int j = 0; j < 4; ++j) yacc[i][j] = (f32x4){0.f, 0.f, 0.f, 0.f};

  auto stageK = [&](int mt) {
    size_t half = (size_t)(mt & 1) * 8192;
#pragma unroll
    for (int dt = 0; dt < 2; ++dt) {
      size_t tile = (tb0 + (size_t)(mt >> 1) * 2 + dt) * 16384 + half;
#pragma unroll
      for (int c = 0; c < 2; ++c) {
        size_t go = (size_t)c * 4096 + w * 1024 + lane * 16;
        glds16(pKh + tile + go, &Kls[dt][0][c * 4096 + w * 1024]);
        glds16(pKl + tile + go, &Kls[dt][1][c * 4096 + w * 1024]);
      }
    }
  };
  auto stageV = [&](int mt) {
    size_t tile = (tb0 + mt) * 16384;
#pragma unroll
    for (int c = 0; c < 4; ++c) {
      size_t go = (size_t)c * 4096 + w * 1024 + lane * 16;
      glds16(pVh + tile + go, &Vls[0][c * 4096 + w * 1024]);
      glds16(pVl + tile + go, &Vls[1][c * 4096 + w * 1024]);
    }
  };

  stageK(0);
  stageV(0);
  __syncthreads();  // drains vmcnt: K,V tile 0 resident

  for (int mt = 0; mt < nt; ++mt) {
    // ---- QK^T: S[n][m], col=m (l15), row=n (lg*4+reg)
    f32x4 sacc[2][2];
#pragma unroll
    for (int i = 0; i < 2; ++i)
#pragma unroll
      for (int j = 0; j < 2; ++j) sacc[i][j] = (f32x4){0.f, 0.f, 0.f, 0.f};
#pragma unroll
    for (int ks = 0; ks < 4; ++ks) {
      int d = ks * 32 + lg * 8;
      bf16x8 kh[2], kl[2];
#pragma unroll
      for (int mf = 0; mf < 2; ++mf) {
        int m = wq * 32 + mf * 16 + l15;
        int off = (m & 63) * 128 + (((d & 63) * 2) ^ ((m & 7) << 4));
        kh[mf] = *(const bf16x8*)&Kls[d >> 6][0][off];
        kl[mf] = *(const bf16x8*)&Kls[d >> 6][1][off];
      }
#pragma unroll
      for (int nf = 0; nf < 2; ++nf)
#pragma unroll
        for (int mf = 0; mf < 2; ++mf) {
          sacc[nf][mf] = __builtin_amdgcn_mfma_f32_16x16x32_bf16(
              qh[nf][ks], kh[mf], sacc[nf][mf], 0, 0, 0);
          sacc[nf][mf] = __builtin_amdgcn_mfma_f32_16x16x32_bf16(
              qh[nf][ks], kl[mf], sacc[nf][mf], 0, 0, 0);
          sacc[nf][mf] = __builtin_amdgcn_mfma_f32_16x16x32_bf16(
              ql[nf][ks], kh[mf], sacc[nf][mf], 0, 0, 0);
        }
    }
    asm volatile("s_barrier" ::: "memory");  // all waves done reading K tile
    if (mt + 1 < nt) stageK(mt + 1);         // async; hides under decay+PV

    // ---- decay + P -> LDS (hi/lo, swizzled)
#pragma unroll
    for (int nf = 0; nf < 2; ++nf)
#pragma unroll
      for (int mf = 0; mf < 2; ++mf)
#pragma unroll
        for (int r = 0; r < 4; ++r) {
          int nl = wn * 32 + nf * 16 + lg * 4 + r;
          int ml = wq * 32 + mf * 16 + l15;
          int diff = (n0 + nl) - (mt * 64 + ml);
          float dec = (diff >= 0) ? exp2f((float)diff * lg2) : 0.0f;
          float p = sacc[nf][mf][r] * dec;
          __bf16 h = (__bf16)p;
          int off = nl * 128 + ((ml * 2) ^ ((nl & 7) << 4));
          *(__bf16*)&Pls[0][off] = h;
          *(__bf16*)&Pls[1][off] = (__bf16)(p - (float)h);
        }
    asm volatile("s_waitcnt lgkmcnt(0)" ::: "memory");
    asm volatile("s_barrier" ::: "memory");  // P visible to all waves

    // ---- PV: Yh[n][d] += P[n][m] V[m][d]
#pragma unroll
    for (int ks = 0; ks < 2; ++ks) {
      int mchunk = ks * 32 + lg * 8;
      bf16x8 ph[2], pl2[2], vh[4], vl2[4];
#pragma unroll
      for (int nf = 0; nf < 2; ++nf) {
        int nl = wn * 32 + nf * 16 + l15;
        int off = nl * 128 + ((mchunk * 2) ^ ((nl & 7) << 4));
        ph[nf]  = *(const bf16x8*)&Pls[0][off];
        pl2[nf] = *(const bf16x8*)&Pls[1][off];
      }
#pragma unroll
      for (int df = 0; df < 4; ++df) {
        int d = wq * 64 + df * 16 + l15;
        int off = d * 128 + ((mchunk * 2) ^ ((d & 7) << 4));
        vh[df]  = *(const bf16x8*)&Vls[0][off];
        vl2[df] = *(const bf16x8*)&Vls[1][off];
      }
#pragma unroll
      for (int nf = 0; nf < 2; ++nf)
#pragma unroll
        for (int df = 0; df < 4; ++df) {
          yacc[nf][df] = __builtin_amdgcn_mfma_f32_16x16x32_bf16(
              ph[nf], vh[df], yacc[nf][df], 0, 0, 0);
          yacc[nf][df] = __builtin_amdgcn_mfma_f32_16x16x32_bf16(
              ph[nf], vl2[df], yacc[nf][df], 0, 0, 0);
          yacc[nf][df] = __builtin_amdgcn_mfma_f32_16x16x32_bf16(
              pl2[nf], vh[df], yacc[nf][df], 0, 0, 0);
        }
    }
    asm volatile("s_barrier" ::: "memory");  // all waves done reading V,P
    if (mt + 1 < nt) stageV(mt + 1);         // async
    __syncthreads();                         // vmcnt drain: next K,V resident
  }

  // ---- epilogue: Y[b][s][h*128+d] fp32
  const size_t yrow0 = (size_t)(bh >> 3) * SS + n0;
  const int hcol = (bh & 7) * HDD;
#pragma unroll
  for (int nf = 0; nf < 2; ++nf)
#pragma unroll
    for (int df = 0; df < 4; ++df)
#pragma unroll
      for (int r = 0; r < 4; ++r) {
        int nl = wn * 32 + nf * 16 + lg * 4 + r;
        int d  = wq * 64 + df * 16 + l15;
        Y[(yrow0 + nl) * DM + hcol + d] = yacc[nf][df][r];
      }
}

// ---------------- GroupNorm * gate -> packed hi/lo swizzled A-operand -------
__global__ __launch_bounds__(256) void gn_gate_k(
    const float* __restrict__ Y, const float* __restrict__ w,
    const float* __restrict__ b, const float* __restrict__ G,
    char* __restrict__ ph, char* __restrict__ pl) {
  int g    = blockIdx.x * 4 + (threadIdx.x >> 6);
  int lane = threadIdx.x & 63;
  float2 v = *(const float2*)(Y + (size_t)g * HDD + lane * 2);
  float s = v.x + v.y, q = v.x * v.x + v.y * v.y;
#pragma unroll
  for (int o = 32; o > 0; o >>= 1) { s += __shfl_xor(s, o); q += __shfl_xor(q, o); }
  float mu  = s * (1.0f / HDD);
  float var = q * (1.0f / HDD) - mu * mu;
  float rs  = 1.0f / sqrtf(var + 1e-5f);
  int m   = g >> 3;
  int col = (g & 7) * HDD + lane * 2;
  float2 wv = *(const float2*)(w + col);
  float2 bv = *(const float2*)(b + col);
  float2 gv = *(const float2*)(G + (size_t)g * HDD + lane * 2);
  float ox = ((v.x - mu) * rs * wv.x + bv.x) * gv.x;
  float oy = ((v.y - mu) * rs * wv.y + bv.y) * gv.y;
  __bf16 hx = (__bf16)ox, hy = (__bf16)oy;
  bf16x2 hv, lv;
  hv[0] = hx; hv[1] = hy;
  lv[0] = (__bf16)(ox - (float)hx); lv[1] = (__bf16)(oy - (float)hy);
  size_t tb = ((size_t)(m >> 7) * (DM / 64) + (col >> 6)) * 16384;
  int off = (m & 127) * 128 + (((col & 63) * 2) ^ ((m & 7) << 4));
  *(bf16x2*)(ph + tb + off) = hv;
  *(bf16x2*)(pl + tb + off) = lv;
}

// ---------------- driver -----------------------------------------------------
extern "C" void kernel_launch(void* const* d_in, const int* in_sizes, int n_in,
                              void* d_out, int out_size, void* d_ws, size_t ws_size,
                              hipStream_t stream) {
  (void)in_sizes; (void)n_in; (void)out_size; (void)ws_size;
  const float* X0   = (const float*)d_in[0];
  const float* ln1w = (const float*)d_in[1];
  const float* ln1b = (const float*)d_in[2];
  const float* ln2w = (const float*)d_in[3];
  const float* ln2b = (const float*)d_in[4];
  const float* WQ   = (const float*)d_in[5];
  const float* WK   = (const float*)d_in[6];
  const float* WV   = (const float*)d_in[7];
  const float* gnw  = (const float*)d_in[8];
  const float* gnb  = (const float*)d_in[9];
  const float* WG   = (const float*)d_in[10];
  const float* WO   = (const float*)d_in[11];
  const float* W1   = (const float*)d_in[12];
  const float* B1   = (const float*)d_in[13];
  const float* W2   = (const float*)d_in[14];
  const float* B2   = (const float*)d_in[15];

  char* wsb = (char*)d_ws;
  const size_t MB = 1 << 20;
  float* bufA = (float*)(wsb + 0 * MB);    // X carry
  float* bufB = (float*)(wsb + 16 * MB);   // Y (WO out / FFN resid)
  float* bufE = (float*)(wsb + 32 * MB);   // V fp32
  float* bufF = (float*)(wsb + 48 * MB);   // gate
  float* bufG = (float*)(wsb + 64 * MB);   // Yh
  float* sq   = (float*)(wsb + 80 * MB);
  float* cq   = (float*)(wsb + 81 * MB);
  float* sk   = (float*)(wsb + 82 * MB);
  float* ck   = (float*)(wsb + 83 * MB);
  float* lg2g = (float*)(wsb + 84 * MB);
  char* pXh = wsb + 85 * MB;
  char* pXl = wsb + 93 * MB;
  char* pWh = wsb + 101 * MB;   // 26 MB
  char* pWl = wsb + 127 * MB;   // 26 MB
  char* R   = wsb + 153 * MB;   // overlap region (64 MB): attn vs FFN phase
  char* pFh = R;                // 32 MB  (FFN phase)
  char* pFl = R + 32 * MB;      // 32 MB
  char* pQh = R;                // 8 MB   (attention phase)
  char* pQl = R + 8 * MB;
  char* pKh = R + 16 * MB;
  char* pKl = R + 24 * MB;
  char* pVh = R + 32 * MB;
  char* pVl = R + 40 * MB;
  const size_t oWQ = 0, oWK = (size_t)2 << 20, oWV = (size_t)4 << 20,
               oWG = (size_t)6 << 20, oWO = (size_t)8 << 20,
               oW1 = (size_t)10 << 20, oW2 = (size_t)18 << 20;

  init_tables_k<<<SS, HDD, 0, stream>>>(sq, cq, sk, ck, lg2g);

  const dim3 g1(8, 32);    // N=1024 GEMMs
  const dim3 gF1(32, 32);  // N=4096
  for (int i = 0; i < LN_; ++i) {
    const float* Xin = (i == 0) ? X0 : bufA;
    packw_k<<<dim3(8, 16), 256, 0, stream>>>(WQ + (size_t)i * 1048576, pWh + oWQ, pWl + oWQ, 1024, 1);
    packw_k<<<dim3(8, 16), 256, 0, stream>>>(WK + (size_t)i * 1048576, pWh + oWK, pWl + oWK, 1024, 1);
    packw_k<<<dim3(8, 16), 256, 0, stream>>>(WV + (size_t)i * 1048576, pWh + oWV, pWl + oWV, 1024, 1);
    packw_k<<<dim3(8, 16), 256, 0, stream>>>(WG + (size_t)i * 1048576, pWh + oWG, pWl + oWG, 1024, 0);
    packw_k<<<dim3(8, 16), 256, 0, stream>>>(WO + (size_t)i * 1048576, pWh + oWO, pWl + oWO, 1024, 0);
    packw_k<<<dim3(32, 16), 256, 0, stream>>>(W1 + (size_t)i * 4194304, pWh + oW1, pWl + oW1, 4096, 0);
    packw_k<<<dim3(8, 64), 256, 0, stream>>>(W2 + (size_t)i * 4194304, pWh + oW2, pWl + oW2, 1024, 0);

    ln_pack_k<<<RR, 256, 0, stream>>>(Xin, ln1w + i * DM, ln1b + i * DM, pXh, pXl);
    mgemm_k<5><<<g1, 256, 0, stream>>>(pXh, pXl, pWh + oWQ, pWl + oWQ, nullptr,
                                       nullptr, nullptr, pQh, pQl, sq, cq, RR, DM, DM);
    mgemm_k<5><<<g1, 256, 0, stream>>>(pXh, pXl, pWh + oWK, pWl + oWK, nullptr,
                                       nullptr, nullptr, pKh, pKl, sk, ck, RR, DM, DM);
    mgemm_k<0><<<g1, 256, 0, stream>>>(pXh, pXl, pWh + oWV, pWl + oWV, bufE,
                                       nullptr, nullptr, nullptr, nullptr, nullptr, nullptr, RR, DM, DM);
    mgemm_k<1><<<g1, 256, 0, stream>>>(pXh, pXl, pWh + oWG, pWl + oWG, bufF,
                                       nullptr, nullptr, nullptr, nullptr, nullptr, nullptr, RR, DM, DM);
    vtpack_k<<<dim3(32, 16), 256, 0, stream>>>(bufE, pVh, pVl);
    mattn_k<<<dim3(32, 16), 256, 0, stream>>>(pQh, pQl, pKh, pKl, pVh, pVl, lg2g, bufG);
    gn_gate_k<<<RR * HH / 4, 256, 0, stream>>>(bufG, gnw + i * DM, gnb + i * DM,
                                               bufF, pXh, pXl);
    mgemm_k<2><<<g1, 256, 0, stream>>>(pXh, pXl, pWh + oWO, pWl + oWO, bufB,
                                       nullptr, Xin, nullptr, nullptr, nullptr, nullptr, RR, DM, DM);
    ln_pack_k<<<RR, 256, 0, stream>>>(bufB, ln2w + i * DM, ln2b + i * DM, pXh, pXl);
    mgemm_k<3><<<gF1, 256, 0, stream>>>(pXh, pXl, pWh + oW1, pWl + oW1, nullptr,
                                        B1 + (size_t)i * FFN_, nullptr, pFh, pFl,
                                        nullptr, nullptr, RR, FFN_, DM);
    float* Xout = (i == LN_ - 1) ? (float*)d_out : bufA;
    mgemm_k<4><<<g1, 256, 0, stream>>>(pFh, pFl, pWh + oW2, pWl + oW2, Xout,
                                       B2 + (size_t)i * DM, bufB, nullptr, nullptr,
                                       nullptr, nullptr, RR, DM, FFN_);
  }
}

// Round 8
// 1190.702 us; speedup vs baseline: 4.1991x; 1.0932x over previous
//
#include <hip/hip_runtime.h>
#include <cstdint>
#include <cstddef>

#define LN_ 2
#define HH 8
#define DM 1024
#define FFN_ 4096
#define HDD 128
#define SS 2048
#define BB 2
#define RR (BB*SS)   // 4096 rows

typedef __bf16 bf16x8 __attribute__((ext_vector_type(8)));
typedef __bf16 bf16x4 __attribute__((ext_vector_type(4)));
typedef __bf16 bf16x2 __attribute__((ext_vector_type(2)));
typedef float  f32x4  __attribute__((ext_vector_type(4)));

__device__ __forceinline__ float silu_f(float x) { return x / (1.0f + expf(-x)); }

// async global->LDS, 16B per lane; LDS dest = wave-uniform base + lane*16
__device__ __forceinline__ void glds16(const void* g, void* l) {
  __builtin_amdgcn_global_load_lds(
      (const __attribute__((address_space(1))) unsigned int*)g,
      (__attribute__((address_space(3))) unsigned int*)l, 16, 0, 0);
}

// Packed operand tiles: [128 rows][64 k] bf16 = 16 KiB, within-tile byte =
// row*128 + ((2*k) ^ ((row&7)<<4)). Producers write this; consumers stage it
// linearly via glds16 and read with the same XOR (both-sides, guide §21).

// ---------------- xPos tables + decay log2-gammas (fp64, matches numpy) -----
__global__ void init_tables_k(float* __restrict__ sq, float* __restrict__ cq,
                              float* __restrict__ sk, float* __restrict__ ck,
                              float* __restrict__ lg2g) {
  int s = blockIdx.x, k = threadIdx.x;
  int j = k >> 1;
  double sv    = (2.0 * j + 0.4 * HDD) / (1.4 * HDD);
  double p     = (double)s / 512.0;
  double scale = pow(sv, p);
  double invf  = pow(10000.0, -((double)j) / 64.0);
  double ang   = (double)s * invf;
  double sn = sin(ang), cs = cos(ang);
  size_t idx = (size_t)s * HDD + k;
  sq[idx] = (float)(sn * scale);
  cq[idx] = (float)(cs * scale);
  sk[idx] = (float)(sn / scale);
  ck[idx] = (float)(cs / scale);
  if (s == 0 && k < HH) {
    double a0 = log(1.0 / 32.0), a1 = log(1.0 / 512.0);
    double x = a0 + (a1 - a0) * ((double)k / 7.0);
    lg2g[k] = (float)(log(1.0 - exp(x)) / log(2.0));
  }
}

// ---------------- LayerNorm -> packed hi/lo swizzled A-operand --------------
__global__ __launch_bounds__(256) void ln_pack_k(
    const float* __restrict__ X, const float* __restrict__ w,
    const float* __restrict__ b, char* __restrict__ ph, char* __restrict__ pl) {
  const int row = blockIdx.x, tid = threadIdx.x;
  const float* x = X + (size_t)row * DM;
  float4 v = *(const float4*)(x + tid * 4);
  float s = v.x + v.y + v.z + v.w;
  float q = v.x * v.x + v.y * v.y + v.z * v.z + v.w * v.w;
#pragma unroll
  for (int o = 32; o > 0; o >>= 1) { s += __shfl_xor(s, o); q += __shfl_xor(q, o); }
  __shared__ float ss[4], qq[4];
  if ((tid & 63) == 0) { ss[tid >> 6] = s; qq[tid >> 6] = q; }
  __syncthreads();
  float S  = ss[0] + ss[1] + ss[2] + ss[3];
  float Qs = qq[0] + qq[1] + qq[2] + qq[3];
  float mu  = S * (1.0f / DM);
  float var = Qs * (1.0f / DM) - mu * mu;
  float rs  = 1.0f / sqrtf(var + 1e-5f);
  float4 wv = *(const float4*)(w + tid * 4);
  float4 bv = *(const float4*)(b + tid * 4);
  float y[4];
  y[0] = (v.x - mu) * rs * wv.x + bv.x;
  y[1] = (v.y - mu) * rs * wv.y + bv.y;
  y[2] = (v.z - mu) * rs * wv.z + bv.z;
  y[3] = (v.w - mu) * rs * wv.w + bv.w;
  bf16x4 hv, lv;
#pragma unroll
  for (int r = 0; r < 4; ++r) {
    __bf16 h = (__bf16)y[r];
    hv[r] = h;
    lv[r] = (__bf16)(y[r] - (float)h);
  }
  size_t tb = ((size_t)(row >> 7) * (DM / 64) + (tid >> 4)) * 16384;
  int off = (row & 127) * 128 + (((tid & 15) * 8) ^ ((row & 7) << 4));
  *(bf16x4*)(ph + tb + off) = hv;
  *(bf16x4*)(pl + tb + off) = lv;
}

// ---------------- Weight pack: fp32 [K][N] -> transposed swizzled hi/lo -----
__global__ __launch_bounds__(256) void packw_k(
    const float* __restrict__ W, char* __restrict__ dh, char* __restrict__ dl,
    int N, int qkv) {
  const int tn = blockIdx.x, tk = blockIdx.y, nkt = gridDim.y;
  __shared__ float L[64][132];
  const int k0 = tk * 64;
  const size_t srcbase = qkv ? ((size_t)tn * 131072 + (size_t)k0 * 128)
                             : ((size_t)k0 * N + (size_t)tn * 128);
  const int rstr = qkv ? 128 : N;
#pragma unroll
  for (int it = 0; it < 8; ++it) {
    int q = threadIdx.x + it * 256;
    int kk = q >> 5, c4 = (q & 31) * 4;
    float4 v = *(const float4*)(W + srcbase + (size_t)kk * rstr + c4);
    *(float4*)&L[kk][c4] = v;
  }
  __syncthreads();
  const size_t tb = ((size_t)tn * nkt + tk) * 16384;
#pragma unroll
  for (int it = 0; it < 4; ++it) {
    int o = threadIdx.x + it * 256;
    int n = o >> 3, k8 = o & 7;
    bf16x8 hv, lv;
#pragma unroll
    for (int j = 0; j < 8; ++j) {
      float x = L[k8 * 8 + j][n];
      __bf16 h = (__bf16)x;
      hv[j] = h;
      lv[j] = (__bf16)(x - (float)h);
    }
    int off = n * 128 + ((k8 * 16) ^ ((n & 7) << 4));
    *(bf16x8*)(dh + tb + off) = hv;
    *(bf16x8*)(dl + tb + off) = lv;
  }
}

// ---------------- V fp32 [b][h][s][d] -> V^T packed tiles (rows=d, k=s) -----
__global__ __launch_bounds__(256) void vtpack_k(
    const float* __restrict__ V, char* __restrict__ dh, char* __restrict__ dl) {
  const int st = blockIdx.x, bh = blockIdx.y;
  __shared__ float L[64][132];
  const float* src = V + ((size_t)bh * SS + st * 64) * HDD;
#pragma unroll
  for (int it = 0; it < 8; ++it) {
    int q = threadIdx.x + it * 256;
    int r = q >> 5, c4 = (q & 31) * 4;
    *(float4*)&L[r][c4] = *(const float4*)(src + (size_t)r * HDD + c4);
  }
  __syncthreads();
  const size_t tb = ((size_t)bh * 32 + st) * 16384;
#pragma unroll
  for (int it = 0; it < 4; ++it) {
    int o = threadIdx.x + it * 256;
    int d = o >> 3, s8 = o & 7;
    bf16x8 hv, lv;
#pragma unroll
    for (int j = 0; j < 8; ++j) {
      float x = L[s8 * 8 + j][d];
      __bf16 h = (__bf16)x;
      hv[j] = h;
      lv[j] = (__bf16)(x - (float)h);
    }
    int off = d * 128 + ((s8 * 16) ^ ((d & 7) << 4));
    *(bf16x8*)(dh + tb + off) = hv;
    *(bf16x8*)(dl + tb + off) = lv;
  }
}

// ---------------- shared split-bf16 GEMM mainloop ---------------------------
// 128m x (NF*32)n tile, BK=64, single-buffered (m97-style): cross-block wave
// overlap hides the barrier drain (needs >=2 blocks/CU).
// acc[nf][mf]: D-row = n (lg*4+reg), D-col = m (l15).
template <int NF>
__device__ __forceinline__ void gemm_main(
    const char* __restrict__ pAh, const char* __restrict__ pAl,
    const char* __restrict__ pBh, const char* __restrict__ pBl,
    size_t tA0, size_t tB0, int nkt, char* lds, f32x4 (&acc)[NF][4]) {
  const int tid = threadIdx.x, lane = tid & 63, w = tid >> 6;
  const int wm = w & 1, wn = w >> 1;
  const int swz = (lane & 7) << 4;
  const int l15 = lane & 15, l4 = lane >> 4;
  char* lAh = lds;
  char* lAl = lds + 16384;
  char* lBh = lds + 32768;
  char* lBl = lds + 32768 + NF * 4096;
  for (int t = 0; t < nkt; ++t) {
    const size_t oA = tA0 + (size_t)t * 16384;
    const size_t oB = tB0 + (size_t)t * 16384;
#pragma unroll
    for (int c = 0; c < 4; ++c) {
      const size_t go = (size_t)c * 4096 + w * 1024 + lane * 16;
      glds16(pAh + oA + go, lAh + c * 4096 + w * 1024);
      glds16(pAl + oA + go, lAl + c * 4096 + w * 1024);
    }
#pragma unroll
    for (int c = 0; c < NF; ++c) {
      const size_t go = (size_t)c * 4096 + w * 1024 + lane * 16;
      glds16(pBh + oB + go, lBh + c * 4096 + w * 1024);
      glds16(pBl + oB + go, lBl + c * 4096 + w * 1024);
    }
    __syncthreads();  // vmcnt(0) drain; co-resident block computes meanwhile
#pragma unroll
    for (int ks = 0; ks < 2; ++ks) {
      const int kb = ks * 64 + l4 * 16;
      bf16x8 amh[4], aml[4], anh[NF], anl[NF];
#pragma unroll
      for (int f = 0; f < 4; ++f) {
        const int ra = (wm * 64 + f * 16 + l15) * 128 + (kb ^ swz);
        amh[f] = *(const bf16x8*)&lAh[ra];
        aml[f] = *(const bf16x8*)&lAl[ra];
      }
#pragma unroll
      for (int f = 0; f < NF; ++f) {
        const int rb = (wn * (NF * 16) + f * 16 + l15) * 128 + (kb ^ swz);
        anh[f] = *(const bf16x8*)&lBh[rb];
        anl[f] = *(const bf16x8*)&lBl[rb];
      }
#pragma unroll
      for (int nf = 0; nf < NF; ++nf)
#pragma unroll
        for (int mf = 0; mf < 4; ++mf) {
          acc[nf][mf] = __builtin_amdgcn_mfma_f32_16x16x32_bf16(
              anh[nf], amh[mf], acc[nf][mf], 0, 0, 0);
          acc[nf][mf] = __builtin_amdgcn_mfma_f32_16x16x32_bf16(
              anh[nf], aml[mf], acc[nf][mf], 0, 0, 0);
          acc[nf][mf] = __builtin_amdgcn_mfma_f32_16x16x32_bf16(
              anl[nf], amh[mf], acc[nf][mf], 0, 0, 0);
        }
    }
    __syncthreads();  // reads done before next stage overwrites
  }
}

// ---------------- GEMM kernels ----------------------------------------------
// MODE 2: + resid -> row-major (WO)    MODE 3: silu(+bias) -> packed (FFN1)
// MODE 4: + bias + resid (FFN2)
template <int MODE, int NF>
__global__ __launch_bounds__(256, (NF == 2 ? 3 : 2)) void mgemm_k(
    const char* __restrict__ pAh, const char* __restrict__ pAl,
    const char* __restrict__ pBh, const char* __restrict__ pBl,
    float* __restrict__ C, const float* __restrict__ bias,
    const float* __restrict__ resid, char* __restrict__ outH,
    char* __restrict__ outL, int N, int K) {
  __shared__ char lds[32768 + NF * 8192];
  const int lane = threadIdx.x & 63, w = threadIdx.x >> 6;
  const int wm = w & 1, wn = w >> 1;
  const int l15 = lane & 15, l4 = lane >> 4;
  const int bx = blockIdx.x, by = blockIdx.y;
  const int nkt = K >> 6;
  const size_t tA0 = (size_t)by * nkt * 16384;
  const size_t tB0 = (NF == 4) ? (size_t)bx * nkt * 16384
                               : (size_t)(bx >> 1) * nkt * 16384 + (size_t)(bx & 1) * 8192;
  f32x4 acc[NF][4];
#pragma unroll
  for (int i = 0; i < NF; ++i)
#pragma unroll
    for (int j = 0; j < 4; ++j) acc[i][j] = (f32x4){0.f, 0.f, 0.f, 0.f};

  gemm_main<NF>(pAh, pAl, pBh, pBl, tA0, tB0, nkt, lds, acc);

  const int mBase = by * 128 + wm * 64 + l15;
  const int nBase = bx * (NF * 32) + wn * (NF * 16) + l4 * 4;
#pragma unroll
  for (int nf = 0; nf < NF; ++nf)
#pragma unroll
    for (int mf = 0; mf < 4; ++mf) {
      const int m = mBase + mf * 16;
      const int n = nBase + nf * 16;
      f32x4 v = acc[nf][mf];
      if (MODE == 2) {
        f32x4 rz = *(const f32x4*)(resid + (size_t)m * N + n);
        v += rz;
        *(f32x4*)(C + (size_t)m * N + n) = v;
      } else if (MODE == 3) {
        f32x4 bz = *(const f32x4*)(bias + n);
        bf16x4 hv, lv;
#pragma unroll
        for (int r = 0; r < 4; ++r) {
          float y = silu_f(v[r] + bz[r]);
          __bf16 h = (__bf16)y;
          hv[r] = h;
          lv[r] = (__bf16)(y - (float)h);
        }
        size_t tb = ((size_t)(m >> 7) * (N >> 6) + (n >> 6)) * 16384;
        int off = (m & 127) * 128 + (((n & 63) * 2) ^ ((m & 7) << 4));
        *(bf16x4*)(outH + tb + off) = hv;
        *(bf16x4*)(outL + tb + off) = lv;
      } else {  // MODE 4
        f32x4 bz = *(const f32x4*)(bias + n);
        f32x4 rz = *(const f32x4*)(resid + (size_t)m * N + n);
        v += bz + rz;
        *(f32x4*)(C + (size_t)m * N + n) = v;
      }
    }
}

// ---------------- Fused QKVG: blockIdx.z selects weight + epilogue ----------
// z=0: Q rotary->packed  z=1: K rotary->packed  z=2: V fp32 [b][h][s][d]
// z=3: silu -> gate row-major. Weights contiguous: offset z*2MB.
__global__ __launch_bounds__(256, 2) void qkvg_k(
    const char* __restrict__ pXh, const char* __restrict__ pXl,
    const char* __restrict__ pWh, const char* __restrict__ pWl,
    float* __restrict__ V, float* __restrict__ G,
    char* __restrict__ pQh, char* __restrict__ pQl,
    char* __restrict__ pKh, char* __restrict__ pKl,
    const float* __restrict__ sq, const float* __restrict__ cq,
    const float* __restrict__ sk, const float* __restrict__ ck) {
  __shared__ char lds[65536];
  const int lane = threadIdx.x & 63, w = threadIdx.x >> 6;
  const int wm = w & 1, wn = w >> 1;
  const int l15 = lane & 15, l4 = lane >> 4;
  const int bx = blockIdx.x, by = blockIdx.y, z = blockIdx.z;
  const int nkt = DM >> 6;  // 16
  const size_t tA0 = (size_t)by * nkt * 16384;
  const size_t tB0 = (size_t)bx * nkt * 16384;
  const size_t wo = (size_t)z << 21;  // z*2MB
  f32x4 acc[4][4];
#pragma unroll
  for (int i = 0; i < 4; ++i)
#pragma unroll
    for (int j = 0; j < 4; ++j) acc[i][j] = (f32x4){0.f, 0.f, 0.f, 0.f};

  gemm_main<4>(pXh, pXl, pWh + wo, pWl + wo, tA0, tB0, nkt, lds, acc);

  const int mBase = by * 128 + wm * 64 + l15;
  const int nBase = bx * 128 + wn * 64 + l4 * 4;
#pragma unroll
  for (int nf = 0; nf < 4; ++nf)
#pragma unroll
    for (int mf = 0; mf < 4; ++mf) {
      const int m = mBase + mf * 16;
      const int n = nBase + nf * 16;
      f32x4 v = acc[nf][mf];
      if (z == 2) {
        *(f32x4*)(V + (((size_t)(m >> 11) * HH + (n >> 7)) * SS + (m & (SS - 1)))
                          * HDD + (n & (HDD - 1))) = v;
      } else if (z == 3) {
#pragma unroll
        for (int r = 0; r < 4; ++r) v[r] = silu_f(v[r]);
        *(f32x4*)(G + (size_t)m * DM + n) = v;
      } else {  // rotary -> packed per-(b,h) tiles (rows=s, k=d)
        const float* tsn = (z == 0) ? sq : sk;
        const float* tcs = (z == 0) ? cq : ck;
        char* oh = (z == 0) ? pQh : pKh;
        char* ol = (z == 0) ? pQl : pKl;
        int s = m & (SS - 1);
        int d = n & (HDD - 1);
        f32x4 sn = *(const f32x4*)(tsn + (size_t)s * HDD + d);
        f32x4 cn = *(const f32x4*)(tcs + (size_t)s * HDD + d);
        float o0 = v[0] * cn[0] - v[1] * sn[0];
        float o1 = v[1] * cn[1] + v[0] * sn[1];
        float o2 = v[2] * cn[2] - v[3] * sn[2];
        float o3 = v[3] * cn[3] + v[2] * sn[3];
        float oo[4] = {o0, o1, o2, o3};
        bf16x4 hv, lv;
#pragma unroll
        for (int r = 0; r < 4; ++r) {
          __bf16 h = (__bf16)oo[r];
          hv[r] = h;
          lv[r] = (__bf16)(oo[r] - (float)h);
        }
        size_t tile = ((size_t)(m >> 11) * HH + (n >> 7)) * 32 + (s >> 7) * 2 + (d >> 6);
        size_t off = tile * 16384 + (s & 127) * 128 + (((d & 63) * 2) ^ ((s & 7) << 4));
        *(bf16x4*)(oh + off) = hv;
        *(bf16x4*)(ol + off) = lv;
      }
    }
}

// ---------------- Retention via split-bf16 MFMA ------------------------------
// grid (32 qt, 16 bh); 256 thr; Q-tile 64 n x 128 d in regs; K/V tiles 64 m.
// LDS 80 KB -> 2 blocks/CU.
__global__ __launch_bounds__(256, 2) void mattn_k(
    const char* __restrict__ pQh, const char* __restrict__ pQl,
    const char* __restrict__ pKh, const char* __restrict__ pKl,
    const char* __restrict__ pVh, const char* __restrict__ pVl,
    const float* __restrict__ lg2g, float* __restrict__ Y) {
  __shared__ char Kls[2][2][8192];   // [dt][hl][64 m rows * 128B]
  __shared__ char Vls[2][16384];     // [hl][128 d rows * 128B]
  __shared__ char Pls[2][8192];      // [hl][64 n rows * 128B]
  const int qt = 31 - blockIdx.x;    // heavy blocks first
  const int bh = blockIdx.y;
  const int tid = threadIdx.x, lane = tid & 63, w = tid >> 6;
  const int wn = w & 1, wq = w >> 1;  // wq = m-half (QK^T) / d-half (PV)
  const int l15 = lane & 15, lg = lane >> 4;
  const float lg2 = lg2g[bh & 7];
  const size_t tb0 = (size_t)bh * 32;
  const int n0 = qt * 64;
  const int nt = qt + 1;

  bf16x8 qh[2][4], ql[2][4];
#pragma unroll
  for (int nf = 0; nf < 2; ++nf) {
    int rr = n0 + wn * 32 + nf * 16 + l15;
    size_t rowbase = (tb0 + (size_t)(rr >> 7) * 2) * 16384 + (size_t)(rr & 127) * 128;
    int sw = (rr & 7) << 4;
#pragma unroll
    for (int ks = 0; ks < 4; ++ks) {
      int d = ks * 32 + lg * 8;
      size_t a = rowbase + (size_t)(d >> 6) * 16384 + (((d & 63) * 2) ^ sw);
      qh[nf][ks] = *(const bf16x8*)(pQh + a);
      ql[nf][ks] = *(const bf16x8*)(pQl + a);
    }
  }

  f32x4 yacc[2][4];
#pragma unroll
  for (int i = 0; i < 2; ++i)
#pragma unroll
    for (int j = 0; j < 4; ++j) yacc[i][j] = (f32x4){0.f, 0.f, 0.f, 0.f};

  auto stageK = [&](int mt) {
    size_t half = (size_t)(mt & 1) * 8192;
#pragma unroll
    for (int dt = 0; dt < 2; ++dt) {
      size_t tile = (tb0 + (size_t)(mt >> 1) * 2 + dt) * 16384 + half;
#pragma unroll
      for (int c = 0; c < 2; ++c) {
        size_t go = (size_t)c * 4096 + w * 1024 + lane * 16;
        glds16(pKh + tile + go, &Kls[dt][0][c * 4096 + w * 1024]);
        glds16(pKl + tile + go, &Kls[dt][1][c * 4096 + w * 1024]);
      }
    }
  };
  auto stageV = [&](int mt) {
    size_t tile = (tb0 + mt) * 16384;
#pragma unroll
    for (int c = 0; c < 4; ++c) {
      size_t go = (size_t)c * 4096 + w * 1024 + lane * 16;
      glds16(pVh + tile + go, &Vls[0][c * 4096 + w * 1024]);
      glds16(pVl + tile + go, &Vls[1][c * 4096 + w * 1024]);
    }
  };

  stageK(0);
  stageV(0);
  __syncthreads();

  for (int mt = 0; mt < nt; ++mt) {
    f32x4 sacc[2][2];
#pragma unroll
    for (int i = 0; i < 2; ++i)
#pragma unroll
      for (int j = 0; j < 2; ++j) sacc[i][j] = (f32x4){0.f, 0.f, 0.f, 0.f};
#pragma unroll
    for (int ks = 0; ks < 4; ++ks) {
      int d = ks * 32 + lg * 8;
      bf16x8 kh[2], kl[2];
#pragma unroll
      for (int mf = 0; mf < 2; ++mf) {
        int m = wq * 32 + mf * 16 + l15;
        int off = (m & 63) * 128 + (((d & 63) * 2) ^ ((m & 7) << 4));
        kh[mf] = *(const bf16x8*)&Kls[d >> 6][0][off];
        kl[mf] = *(const bf16x8*)&Kls[d >> 6][1][off];
      }
#pragma unroll
      for (int nf = 0; nf < 2; ++nf)
#pragma unroll
        for (int mf = 0; mf < 2; ++mf) {
          sacc[nf][mf] = __builtin_amdgcn_mfma_f32_16x16x32_bf16(
              qh[nf][ks], kh[mf], sacc[nf][mf], 0, 0, 0);
          sacc[nf][mf] = __builtin_amdgcn_mfma_f32_16x16x32_bf16(
              qh[nf][ks], kl[mf], sacc[nf][mf], 0, 0, 0);
          sacc[nf][mf] = __builtin_amdgcn_mfma_f32_16x16x32_bf16(
              ql[nf][ks], kh[mf], sacc[nf][mf], 0, 0, 0);
        }
    }
    asm volatile("s_barrier" ::: "memory");
    if (mt + 1 < nt) stageK(mt + 1);

#pragma unroll
    for (int nf = 0; nf < 2; ++nf)
#pragma unroll
      for (int mf = 0; mf < 2; ++mf)
#pragma unroll
        for (int r = 0; r < 4; ++r) {
          int nl = wn * 32 + nf * 16 + lg * 4 + r;
          int ml = wq * 32 + mf * 16 + l15;
          int diff = (n0 + nl) - (mt * 64 + ml);
          float dec = (diff >= 0) ? exp2f((float)diff * lg2) : 0.0f;
          float p = sacc[nf][mf][r] * dec;
          __bf16 h = (__bf16)p;
          int off = nl * 128 + ((ml * 2) ^ ((nl & 7) << 4));
          *(__bf16*)&Pls[0][off] = h;
          *(__bf16*)&Pls[1][off] = (__bf16)(p - (float)h);
        }
    asm volatile("s_waitcnt lgkmcnt(0)" ::: "memory");
    asm volatile("s_barrier" ::: "memory");

#pragma unroll
    for (int ks = 0; ks < 2; ++ks) {
      int mchunk = ks * 32 + lg * 8;
      bf16x8 ph[2], pl2[2], vh[4], vl2[4];
#pragma unroll
      for (int nf = 0; nf < 2; ++nf) {
        int nl = wn * 32 + nf * 16 + l15;
        int off = nl * 128 + ((mchunk * 2) ^ ((nl & 7) << 4));
        ph[nf]  = *(const bf16x8*)&Pls[0][off];
        pl2[nf] = *(const bf16x8*)&Pls[1][off];
      }
#pragma unroll
      for (int df = 0; df < 4; ++df) {
        int d = wq * 64 + df * 16 + l15;
        int off = d * 128 + ((mchunk * 2) ^ ((d & 7) << 4));
        vh[df]  = *(const bf16x8*)&Vls[0][off];
        vl2[df] = *(const bf16x8*)&Vls[1][off];
      }
#pragma unroll
      for (int nf = 0; nf < 2; ++nf)
#pragma unroll
        for (int df = 0; df < 4; ++df) {
          yacc[nf][df] = __builtin_amdgcn_mfma_f32_16x16x32_bf16(
              ph[nf], vh[df], yacc[nf][df], 0, 0, 0);
          yacc[nf][df] = __builtin_amdgcn_mfma_f32_16x16x32_bf16(
              ph[nf], vl2[df], yacc[nf][df], 0, 0, 0);
          yacc[nf][df] = __builtin_amdgcn_mfma_f32_16x16x32_bf16(
              pl2[nf], vh[df], yacc[nf][df], 0, 0, 0);
        }
    }
    asm volatile("s_barrier" ::: "memory");
    if (mt + 1 < nt) stageV(mt + 1);
    __syncthreads();
  }

  const size_t yrow0 = (size_t)(bh >> 3) * SS + n0;
  const int hcol = (bh & 7) * HDD;
#pragma unroll
  for (int nf = 0; nf < 2; ++nf)
#pragma unroll
    for (int df = 0; df < 4; ++df)
#pragma unroll
      for (int r = 0; r < 4; ++r) {
        int nl = wn * 32 + nf * 16 + lg * 4 + r;
        int d  = wq * 64 + df * 16 + l15;
        Y[(yrow0 + nl) * DM + hcol + d] = yacc[nf][df][r];
      }
}

// ---------------- GroupNorm * gate -> packed hi/lo swizzled A-operand -------
__global__ __launch_bounds__(256) void gn_gate_k(
    const float* __restrict__ Y, const float* __restrict__ w,
    const float* __restrict__ b, const float* __restrict__ G,
    char* __restrict__ ph, char* __restrict__ pl) {
  int g    = blockIdx.x * 4 + (threadIdx.x >> 6);
  int lane = threadIdx.x & 63;
  float2 v = *(const float2*)(Y + (size_t)g * HDD + lane * 2);
  float s = v.x + v.y, q = v.x * v.x + v.y * v.y;
#pragma unroll
  for (int o = 32; o > 0; o >>= 1) { s += __shfl_xor(s, o); q += __shfl_xor(q, o); }
  float mu  = s * (1.0f / HDD);
  float var = q * (1.0f / HDD) - mu * mu;
  float rs  = 1.0f / sqrtf(var + 1e-5f);
  int m   = g >> 3;
  int col = (g & 7) * HDD + lane * 2;
  float2 wv = *(const float2*)(w + col);
  float2 bv = *(const float2*)(b + col);
  float2 gv = *(const float2*)(G + (size_t)g * HDD + lane * 2);
  float ox = ((v.x - mu) * rs * wv.x + bv.x) * gv.x;
  float oy = ((v.y - mu) * rs * wv.y + bv.y) * gv.y;
  __bf16 hx = (__bf16)ox, hy = (__bf16)oy;
  bf16x2 hv, lv;
  hv[0] = hx; hv[1] = hy;
  lv[0] = (__bf16)(ox - (float)hx); lv[1] = (__bf16)(oy - (float)hy);
  size_t tb = ((size_t)(m >> 7) * (DM / 64) + (col >> 6)) * 16384;
  int off = (m & 127) * 128 + (((col & 63) * 2) ^ ((m & 7) << 4));
  *(bf16x2*)(ph + tb + off) = hv;
  *(bf16x2*)(pl + tb + off) = lv;
}

// ---------------- driver -----------------------------------------------------
extern "C" void kernel_launch(void* const* d_in, const int* in_sizes, int n_in,
                              void* d_out, int out_size, void* d_ws, size_t ws_size,
                              hipStream_t stream) {
  (void)in_sizes; (void)n_in; (void)out_size; (void)ws_size;
  const float* X0   = (const float*)d_in[0];
  const float* ln1w = (const float*)d_in[1];
  const float* ln1b = (const float*)d_in[2];
  const float* ln2w = (const float*)d_in[3];
  const float* ln2b = (const float*)d_in[4];
  const float* WQ   = (const float*)d_in[5];
  const float* WK   = (const float*)d_in[6];
  const float* WV   = (const float*)d_in[7];
  const float* gnw  = (const float*)d_in[8];
  const float* gnb  = (const float*)d_in[9];
  const float* WG   = (const float*)d_in[10];
  const float* WO   = (const float*)d_in[11];
  const float* W1   = (const float*)d_in[12];
  const float* B1   = (const float*)d_in[13];
  const float* W2   = (const float*)d_in[14];
  const float* B2   = (const float*)d_in[15];

  char* wsb = (char*)d_ws;
  const size_t MB = 1 << 20;
  float* bufA = (float*)(wsb + 0 * MB);    // X carry
  float* bufB = (float*)(wsb + 16 * MB);   // Y (WO out / FFN resid)
  float* bufE = (float*)(wsb + 32 * MB);   // V fp32
  float* bufF = (float*)(wsb + 48 * MB);   // gate
  float* bufG = (float*)(wsb + 64 * MB);   // Yh
  float* sq   = (float*)(wsb + 80 * MB);
  float* cq   = (float*)(wsb + 81 * MB);
  float* sk   = (float*)(wsb + 82 * MB);
  float* ck   = (float*)(wsb + 83 * MB);
  float* lg2g = (float*)(wsb + 84 * MB);
  char* pXh = wsb + 85 * MB;
  char* pXl = wsb + 93 * MB;
  char* pWh = wsb + 101 * MB;   // 26 MB (Q,K,V,G,O contiguous 2MB each; W1 8MB; W2 8MB)
  char* pWl = wsb + 127 * MB;   // 26 MB
  char* R   = wsb + 153 * MB;   // overlap region: attn phase vs FFN phase
  char* pFh = R;                // 32 MB (FFN)
  char* pFl = R + 32 * MB;
  char* pQh = R;                // 8 MB (attention)
  char* pQl = R + 8 * MB;
  char* pKh = R + 16 * MB;
  char* pKl = R + 24 * MB;
  char* pVh = R + 32 * MB;
  char* pVl = R + 40 * MB;
  const size_t oWQ = 0, oW1 = (size_t)10 << 20, oWO = (size_t)8 << 20,
               oW2 = (size_t)18 << 20;

  init_tables_k<<<SS, HDD, 0, stream>>>(sq, cq, sk, ck, lg2g);

  for (int i = 0; i < LN_; ++i) {
    const float* Xin = (i == 0) ? X0 : bufA;
    // pack layer weights: Q,K,V,G consecutive (2MB each), then O, W1, W2
    packw_k<<<dim3(8, 16), 256, 0, stream>>>(WQ + (size_t)i * 1048576, pWh + oWQ, pWl + oWQ, 1024, 1);
    packw_k<<<dim3(8, 16), 256, 0, stream>>>(WK + (size_t)i * 1048576, pWh + 2 * MB, pWl + 2 * MB, 1024, 1);
    packw_k<<<dim3(8, 16), 256, 0, stream>>>(WV + (size_t)i * 1048576, pWh + 4 * MB, pWl + 4 * MB, 1024, 1);
    packw_k<<<dim3(8, 16), 256, 0, stream>>>(WG + (size_t)i * 1048576, pWh + 6 * MB, pWl + 6 * MB, 1024, 0);
    packw_k<<<dim3(8, 16), 256, 0, stream>>>(WO + (size_t)i * 1048576, pWh + oWO, pWl + oWO, 1024, 0);
    packw_k<<<dim3(32, 16), 256, 0, stream>>>(W1 + (size_t)i * 4194304, pWh + oW1, pWl + oW1, 4096, 0);
    packw_k<<<dim3(8, 64), 256, 0, stream>>>(W2 + (size_t)i * 4194304, pWh + oW2, pWl + oW2, 1024, 0);

    ln_pack_k<<<RR, 256, 0, stream>>>(Xin, ln1w + i * DM, ln1b + i * DM, pXh, pXl);
    qkvg_k<<<dim3(8, 32, 4), 256, 0, stream>>>(pXh, pXl, pWh, pWl, bufE, bufF,
                                               pQh, pQl, pKh, pKl, sq, cq, sk, ck);
    vtpack_k<<<dim3(32, 16), 256, 0, stream>>>(bufE, pVh, pVl);
    mattn_k<<<dim3(32, 16), 256, 0, stream>>>(pQh, pQl, pKh, pKl, pVh, pVl, lg2g, bufG);
    gn_gate_k<<<RR * HH / 4, 256, 0, stream>>>(bufG, gnw + i * DM, gnb + i * DM,
                                               bufF, pXh, pXl);
    mgemm_k<2, 2><<<dim3(16, 32), 256, 0, stream>>>(pXh, pXl, pWh + oWO, pWl + oWO,
                                                    bufB, nullptr, Xin, nullptr, nullptr,
                                                    DM, DM);
    ln_pack_k<<<RR, 256, 0, stream>>>(bufB, ln2w + i * DM, ln2b + i * DM, pXh, pXl);
    mgemm_k<3, 4><<<dim3(32, 32), 256, 0, stream>>>(pXh, pXl, pWh + oW1, pWl + oW1,
                                                    nullptr, B1 + (size_t)i * FFN_,
                                                    nullptr, pFh, pFl, FFN_, DM);
    float* Xout = (i == LN_ - 1) ? (float*)d_out : bufA;
    mgemm_k<4, 2><<<dim3(16, 32), 256, 0, stream>>>(pFh, pFl, pWh + oW2, pWl + oW2,
                                                    Xout, B2 + (size_t)i * DM, bufB,
                                                    nullptr, nullptr, DM, FFN_);
  }
}

// Round 10
// 1105.413 us; speedup vs baseline: 4.5230x; 1.0772x over previous
//
#include <hip/hip_runtime.h>
#include <cstdint>
#include <cstddef>

#define LN_ 2
#define HH 8
#define DM 1024
#define FFN_ 4096
#define HDD 128
#define SS 2048
#define BB 2
#define RR (BB*SS)   // 4096 rows

typedef __bf16 bf16x8 __attribute__((ext_vector_type(8)));
typedef __bf16 bf16x4 __attribute__((ext_vector_type(4)));
typedef __bf16 bf16x2 __attribute__((ext_vector_type(2)));
typedef float  f32x4  __attribute__((ext_vector_type(4)));

__device__ __forceinline__ float silu_f(float x) { return x / (1.0f + expf(-x)); }

// async global->LDS, 16B per lane; LDS dest = wave-uniform base + lane*16
__device__ __forceinline__ void glds16(const void* g, void* l) {
  __builtin_amdgcn_global_load_lds(
      (const __attribute__((address_space(1))) unsigned int*)g,
      (__attribute__((address_space(3))) unsigned int*)l, 16, 0, 0);
}

// Packed operand tiles: [128 rows][64 k] bf16 = 16 KiB, within-tile byte =
// row*128 + ((2*k) ^ ((row&7)<<4)). Producers write this; consumers stage it
// linearly via glds16 and read with the same XOR (both-sides, guide §21).

// XCD swizzle (T1): dispatcher round-robins consecutive blocks over 8 XCDs;
// remap so each XCD gets a CONTIGUOUS logical chunk -> shared operand strips
// hit its private L2 instead of being re-fetched by all 8. Bijective when
// nblk % 8 == 0 (all our grids are).
__device__ __forceinline__ int xcd_swz(int lin, int nblk) {
  return (lin & 7) * (nblk >> 3) + (lin >> 3);
}

// ---------------- xPos tables + decay log2-gammas (fp64, matches numpy) -----
__global__ void init_tables_k(float* __restrict__ sq, float* __restrict__ cq,
                              float* __restrict__ sk, float* __restrict__ ck,
                              float* __restrict__ lg2g) {
  int s = blockIdx.x, k = threadIdx.x;
  int j = k >> 1;
  double sv    = (2.0 * j + 0.4 * HDD) / (1.4 * HDD);
  double p     = (double)s / 512.0;
  double scale = pow(sv, p);
  double invf  = pow(10000.0, -((double)j) / 64.0);
  double ang   = (double)s * invf;
  double sn = sin(ang), cs = cos(ang);
  size_t idx = (size_t)s * HDD + k;
  sq[idx] = (float)(sn * scale);
  cq[idx] = (float)(cs * scale);
  sk[idx] = (float)(sn / scale);
  ck[idx] = (float)(cs / scale);
  if (s == 0 && k < HH) {
    double a0 = log(1.0 / 32.0), a1 = log(1.0 / 512.0);
    double x = a0 + (a1 - a0) * ((double)k / 7.0);
    lg2g[k] = (float)(log(1.0 - exp(x)) / log(2.0));
  }
}

// ---------------- LayerNorm -> packed hi/lo swizzled A-operand --------------
__global__ __launch_bounds__(256) void ln_pack_k(
    const float* __restrict__ X, const float* __restrict__ w,
    const float* __restrict__ b, char* __restrict__ ph, char* __restrict__ pl) {
  const int row = blockIdx.x, tid = threadIdx.x;
  const float* x = X + (size_t)row * DM;
  float4 v = *(const float4*)(x + tid * 4);
  float s = v.x + v.y + v.z + v.w;
  float q = v.x * v.x + v.y * v.y + v.z * v.z + v.w * v.w;
#pragma unroll
  for (int o = 32; o > 0; o >>= 1) { s += __shfl_xor(s, o); q += __shfl_xor(q, o); }
  __shared__ float ss[4], qq[4];
  if ((tid & 63) == 0) { ss[tid >> 6] = s; qq[tid >> 6] = q; }
  __syncthreads();
  float S  = ss[0] + ss[1] + ss[2] + ss[3];
  float Qs = qq[0] + qq[1] + qq[2] + qq[3];
  float mu  = S * (1.0f / DM);
  float var = Qs * (1.0f / DM) - mu * mu;
  float rs  = 1.0f / sqrtf(var + 1e-5f);
  float4 wv = *(const float4*)(w + tid * 4);
  float4 bv = *(const float4*)(b + tid * 4);
  float y[4];
  y[0] = (v.x - mu) * rs * wv.x + bv.x;
  y[1] = (v.y - mu) * rs * wv.y + bv.y;
  y[2] = (v.z - mu) * rs * wv.z + bv.z;
  y[3] = (v.w - mu) * rs * wv.w + bv.w;
  bf16x4 hv, lv;
#pragma unroll
  for (int r = 0; r < 4; ++r) {
    __bf16 h = (__bf16)y[r];
    hv[r] = h;
    lv[r] = (__bf16)(y[r] - (float)h);
  }
  size_t tb = ((size_t)(row >> 7) * (DM / 64) + (tid >> 4)) * 16384;
  int off = (row & 127) * 128 + (((tid & 15) * 8) ^ ((row & 7) << 4));
  *(bf16x4*)(ph + tb + off) = hv;
  *(bf16x4*)(pl + tb + off) = lv;
}

// ---------------- Weight pack: fp32 [K][N] -> transposed swizzled hi/lo -----
__global__ __launch_bounds__(256) void packw_k(
    const float* __restrict__ W, char* __restrict__ dh, char* __restrict__ dl,
    int N, int qkv) {
  const int tn = blockIdx.x, tk = blockIdx.y, nkt = gridDim.y;
  __shared__ float L[64][132];
  const int k0 = tk * 64;
  const size_t srcbase = qkv ? ((size_t)tn * 131072 + (size_t)k0 * 128)
                             : ((size_t)k0 * N + (size_t)tn * 128);
  const int rstr = qkv ? 128 : N;
#pragma unroll
  for (int it = 0; it < 8; ++it) {
    int q = threadIdx.x + it * 256;
    int kk = q >> 5, c4 = (q & 31) * 4;
    float4 v = *(const float4*)(W + srcbase + (size_t)kk * rstr + c4);
    *(float4*)&L[kk][c4] = v;
  }
  __syncthreads();
  const size_t tb = ((size_t)tn * nkt + tk) * 16384;
#pragma unroll
  for (int it = 0; it < 4; ++it) {
    int o = threadIdx.x + it * 256;
    int n = o >> 3, k8 = o & 7;
    bf16x8 hv, lv;
#pragma unroll
    for (int j = 0; j < 8; ++j) {
      float x = L[k8 * 8 + j][n];
      __bf16 h = (__bf16)x;
      hv[j] = h;
      lv[j] = (__bf16)(x - (float)h);
    }
    int off = n * 128 + ((k8 * 16) ^ ((n & 7) << 4));
    *(bf16x8*)(dh + tb + off) = hv;
    *(bf16x8*)(dl + tb + off) = lv;
  }
}

// ---------------- V fp32 [b][h][s][d] -> V^T packed tiles (rows=d, k=s) -----
__global__ __launch_bounds__(256) void vtpack_k(
    const float* __restrict__ V, char* __restrict__ dh, char* __restrict__ dl) {
  const int st = blockIdx.x, bh = blockIdx.y;
  __shared__ float L[64][132];
  const float* src = V + ((size_t)bh * SS + st * 64) * HDD;
#pragma unroll
  for (int it = 0; it < 8; ++it) {
    int q = threadIdx.x + it * 256;
    int r = q >> 5, c4 = (q & 31) * 4;
    *(float4*)&L[r][c4] = *(const float4*)(src + (size_t)r * HDD + c4);
  }
  __syncthreads();
  const size_t tb = ((size_t)bh * 32 + st) * 16384;
#pragma unroll
  for (int it = 0; it < 4; ++it) {
    int o = threadIdx.x + it * 256;
    int d = o >> 3, s8 = o & 7;
    bf16x8 hv, lv;
#pragma unroll
    for (int j = 0; j < 8; ++j) {
      float x = L[s8 * 8 + j][d];
      __bf16 h = (__bf16)x;
      hv[j] = h;
      lv[j] = (__bf16)(x - (float)h);
    }
    int off = d * 128 + ((s8 * 16) ^ ((d & 7) << 4));
    *(bf16x8*)(dh + tb + off) = hv;
    *(bf16x8*)(dl + tb + off) = lv;
  }
}

// ---------------- shared split-bf16 GEMM mainloop ---------------------------
// 128m x (NF*32)n tile, BK=64, single-buffered (m97-style): cross-block wave
// overlap hides the barrier drain (needs >=2 blocks/CU).
// acc[nf][mf]: D-row = n (lg*4+reg), D-col = m (l15).
template <int NF>
__device__ __forceinline__ void gemm_main(
    const char* __restrict__ pAh, const char* __restrict__ pAl,
    const char* __restrict__ pBh, const char* __restrict__ pBl,
    size_t tA0, size_t tB0, int nkt, char* lds, f32x4 (&acc)[NF][4]) {
  const int tid = threadIdx.x, lane = tid & 63, w = tid >> 6;
  const int wm = w & 1, wn = w >> 1;
  const int swz = (lane & 7) << 4;
  const int l15 = lane & 15, l4 = lane >> 4;
  char* lAh = lds;
  char* lAl = lds + 16384;
  char* lBh = lds + 32768;
  char* lBl = lds + 32768 + NF * 4096;
  for (int t = 0; t < nkt; ++t) {
    const size_t oA = tA0 + (size_t)t * 16384;
    const size_t oB = tB0 + (size_t)t * 16384;
#pragma unroll
    for (int c = 0; c < 4; ++c) {
      const size_t go = (size_t)c * 4096 + w * 1024 + lane * 16;
      glds16(pAh + oA + go, lAh + c * 4096 + w * 1024);
      glds16(pAl + oA + go, lAl + c * 4096 + w * 1024);
    }
#pragma unroll
    for (int c = 0; c < NF; ++c) {
      const size_t go = (size_t)c * 4096 + w * 1024 + lane * 16;
      glds16(pBh + oB + go, lBh + c * 4096 + w * 1024);
      glds16(pBl + oB + go, lBl + c * 4096 + w * 1024);
    }
    __syncthreads();  // vmcnt(0) drain; co-resident block computes meanwhile
#pragma unroll
    for (int ks = 0; ks < 2; ++ks) {
      const int kb = ks * 64 + l4 * 16;
      bf16x8 amh[4], aml[4], anh[NF], anl[NF];
#pragma unroll
      for (int f = 0; f < 4; ++f) {
        const int ra = (wm * 64 + f * 16 + l15) * 128 + (kb ^ swz);
        amh[f] = *(const bf16x8*)&lAh[ra];
        aml[f] = *(const bf16x8*)&lAl[ra];
      }
#pragma unroll
      for (int f = 0; f < NF; ++f) {
        const int rb = (wn * (NF * 16) + f * 16 + l15) * 128 + (kb ^ swz);
        anh[f] = *(const bf16x8*)&lBh[rb];
        anl[f] = *(const bf16x8*)&lBl[rb];
      }
#pragma unroll
      for (int nf = 0; nf < NF; ++nf)
#pragma unroll
        for (int mf = 0; mf < 4; ++mf) {
          acc[nf][mf] = __builtin_amdgcn_mfma_f32_16x16x32_bf16(
              anh[nf], amh[mf], acc[nf][mf], 0, 0, 0);
          acc[nf][mf] = __builtin_amdgcn_mfma_f32_16x16x32_bf16(
              anh[nf], aml[mf], acc[nf][mf], 0, 0, 0);
          acc[nf][mf] = __builtin_amdgcn_mfma_f32_16x16x32_bf16(
              anl[nf], amh[mf], acc[nf][mf], 0, 0, 0);
        }
    }
    __syncthreads();  // reads done before next stage overwrites
  }
}

// ---------------- GEMM kernels ----------------------------------------------
// MODE 2: + resid -> row-major (WO)    MODE 3: silu(+bias) -> packed (FFN1)
// MODE 4: + bias + resid (FFN2)
template <int MODE, int NF>
__global__ __launch_bounds__(256, (NF == 2 ? 3 : 2)) void mgemm_k(
    const char* __restrict__ pAh, const char* __restrict__ pAl,
    const char* __restrict__ pBh, const char* __restrict__ pBl,
    float* __restrict__ C, const float* __restrict__ bias,
    const float* __restrict__ resid, char* __restrict__ outH,
    char* __restrict__ outL, int N, int K) {
  __shared__ char lds[32768 + NF * 8192];
  const int lane = threadIdx.x & 63, w = threadIdx.x >> 6;
  const int wm = w & 1, wn = w >> 1;
  const int l15 = lane & 15, l4 = lane >> 4;
  // XCD-swizzled block -> logical tile mapping (T1)
  const int lin = blockIdx.y * gridDim.x + blockIdx.x;
  const int swzb = xcd_swz(lin, gridDim.x * gridDim.y);
  const int bx = swzb % gridDim.x, by = swzb / gridDim.x;
  const int nkt = K >> 6;
  const size_t tA0 = (size_t)by * nkt * 16384;
  const size_t tB0 = (NF == 4) ? (size_t)bx * nkt * 16384
                               : (size_t)(bx >> 1) * nkt * 16384 + (size_t)(bx & 1) * 8192;
  f32x4 acc[NF][4];
#pragma unroll
  for (int i = 0; i < NF; ++i)
#pragma unroll
    for (int j = 0; j < 4; ++j) acc[i][j] = (f32x4){0.f, 0.f, 0.f, 0.f};

  gemm_main<NF>(pAh, pAl, pBh, pBl, tA0, tB0, nkt, lds, acc);

  const int mBase = by * 128 + wm * 64 + l15;
  const int nBase = bx * (NF * 32) + wn * (NF * 16) + l4 * 4;
#pragma unroll
  for (int nf = 0; nf < NF; ++nf)
#pragma unroll
    for (int mf = 0; mf < 4; ++mf) {
      const int m = mBase + mf * 16;
      const int n = nBase + nf * 16;
      f32x4 v = acc[nf][mf];
      if (MODE == 2) {
        f32x4 rz = *(const f32x4*)(resid + (size_t)m * N + n);
        v += rz;
        *(f32x4*)(C + (size_t)m * N + n) = v;
      } else if (MODE == 3) {
        f32x4 bz = *(const f32x4*)(bias + n);
        bf16x4 hv, lv;
#pragma unroll
        for (int r = 0; r < 4; ++r) {
          float y = silu_f(v[r] + bz[r]);
          __bf16 h = (__bf16)y;
          hv[r] = h;
          lv[r] = (__bf16)(y - (float)h);
        }
        size_t tb = ((size_t)(m >> 7) * (N >> 6) + (n >> 6)) * 16384;
        int off = (m & 127) * 128 + (((n & 63) * 2) ^ ((m & 7) << 4));
        *(bf16x4*)(outH + tb + off) = hv;
        *(bf16x4*)(outL + tb + off) = lv;
      } else {  // MODE 4
        f32x4 bz = *(const f32x4*)(bias + n);
        f32x4 rz = *(const f32x4*)(resid + (size_t)m * N + n);
        v += bz + rz;
        *(f32x4*)(C + (size_t)m * N + n) = v;
      }
    }
}

// ---------------- Fused QKVG: z selects weight + epilogue -------------------
// z=0: Q rotary->packed  z=1: K rotary->packed  z=2: V fp32 [b][h][s][d]
// z=3: silu -> gate row-major. Weights contiguous: offset z*2MB.
__global__ __launch_bounds__(256, 2) void qkvg_k(
    const char* __restrict__ pXh, const char* __restrict__ pXl,
    const char* __restrict__ pWh, const char* __restrict__ pWl,
    float* __restrict__ V, float* __restrict__ G,
    char* __restrict__ pQh, char* __restrict__ pQl,
    char* __restrict__ pKh, char* __restrict__ pKl,
    const float* __restrict__ sq, const float* __restrict__ cq,
    const float* __restrict__ sk, const float* __restrict__ ck) {
  __shared__ char lds[65536];
  const int lane = threadIdx.x & 63, w = threadIdx.x >> 6;
  const int wm = w & 1, wn = w >> 1;
  const int l15 = lane & 15, l4 = lane >> 4;
  // XCD-swizzled (bx,by,z): grid 8x32x4 = 1024 blocks, chunk 128/XCD
  const int lin = ((blockIdx.z * 32) + blockIdx.y) * 8 + blockIdx.x;
  const int swzb = xcd_swz(lin, 1024);
  const int bx = swzb & 7, by = (swzb >> 3) & 31, z = swzb >> 8;
  const int nkt = DM >> 6;  // 16
  const size_t tA0 = (size_t)by * nkt * 16384;
  const size_t tB0 = (size_t)bx * nkt * 16384;
  const size_t wo = (size_t)z << 21;  // z*2MB
  f32x4 acc[4][4];
#pragma unroll
  for (int i = 0; i < 4; ++i)
#pragma unroll
    for (int j = 0; j < 4; ++j) acc[i][j] = (f32x4){0.f, 0.f, 0.f, 0.f};

  gemm_main<4>(pXh, pXl, pWh + wo, pWl + wo, tA0, tB0, nkt, lds, acc);

  const int mBase = by * 128 + wm * 64 + l15;
  const int nBase = bx * 128 + wn * 64 + l4 * 4;
#pragma unroll
  for (int nf = 0; nf < 4; ++nf)
#pragma unroll
    for (int mf = 0; mf < 4; ++mf) {
      const int m = mBase + mf * 16;
      const int n = nBase + nf * 16;
      f32x4 v = acc[nf][mf];
      if (z == 2) {
        *(f32x4*)(V + (((size_t)(m >> 11) * HH + (n >> 7)) * SS + (m & (SS - 1)))
                          * HDD + (n & (HDD - 1))) = v;
      } else if (z == 3) {
#pragma unroll
        for (int r = 0; r < 4; ++r) v[r] = silu_f(v[r]);
        *(f32x4*)(G + (size_t)m * DM + n) = v;
      } else {  // rotary -> packed per-(b,h) tiles (rows=s, k=d)
        const float* tsn = (z == 0) ? sq : sk;
        const float* tcs = (z == 0) ? cq : ck;
        char* oh = (z == 0) ? pQh : pKh;
        char* ol = (z == 0) ? pQl : pKl;
        int s = m & (SS - 1);
        int d = n & (HDD - 1);
        f32x4 sn = *(const f32x4*)(tsn + (size_t)s * HDD + d);
        f32x4 cn = *(const f32x4*)(tcs + (size_t)s * HDD + d);
        float o0 = v[0] * cn[0] - v[1] * sn[0];
        float o1 = v[1] * cn[1] + v[0] * sn[1];
        float o2 = v[2] * cn[2] - v[3] * sn[2];
        float o3 = v[3] * cn[3] + v[2] * sn[3];
        float oo[4] = {o0, o1, o2, o3};
        bf16x4 hv, lv;
#pragma unroll
        for (int r = 0; r < 4; ++r) {
          __bf16 h = (__bf16)oo[r];
          hv[r] = h;
          lv[r] = (__bf16)(oo[r] - (float)h);
        }
        size_t tile = ((size_t)(m >> 11) * HH + (n >> 7)) * 32 + (s >> 7) * 2 + (d >> 6);
        size_t off = tile * 16384 + (s & 127) * 128 + (((d & 63) * 2) ^ ((s & 7) << 4));
        *(bf16x4*)(oh + off) = hv;
        *(bf16x4*)(ol + off) = lv;
      }
    }
}

// ---------------- Retention via split-bf16 MFMA ------------------------------
// grid (32 qt, 16 bh); 256 thr; Q-tile 64 n x 128 d in regs; K/V tiles 64 m.
// LDS 80 KB -> 2 blocks/CU.
__global__ __launch_bounds__(256, 2) void mattn_k(
    const char* __restrict__ pQh, const char* __restrict__ pQl,
    const char* __restrict__ pKh, const char* __restrict__ pKl,
    const char* __restrict__ pVh, const char* __restrict__ pVl,
    const float* __restrict__ lg2g, float* __restrict__ Y) {
  __shared__ char Kls[2][2][8192];   // [dt][hl][64 m rows * 128B]
  __shared__ char Vls[2][16384];     // [hl][128 d rows * 128B]
  __shared__ char Pls[2][8192];      // [hl][64 n rows * 128B]
  // XCD-swizzled: 512 blocks -> 64/XCD = 2 bh x 32 qt (K/V strips L2-local);
  // heavy-first qt order preserved within each chunk.
  const int lin = blockIdx.y * 32 + blockIdx.x;
  const int swzb = xcd_swz(lin, 512);
  const int qt = 31 - (swzb & 31);
  const int bh = swzb >> 5;
  const int tid = threadIdx.x, lane = tid & 63, w = tid >> 6;
  const int wn = w & 1, wq = w >> 1;  // wq = m-half (QK^T) / d-half (PV)
  const int l15 = lane & 15, lg = lane >> 4;
  const float lg2 = lg2g[bh & 7];
  const size_t tb0 = (size_t)bh * 32;
  const int n0 = qt * 64;
  const int nt = qt + 1;

  bf16x8 qh[2][4], ql[2][4];
#pragma unroll
  for (int nf = 0; nf < 2; ++nf) {
    int rr = n0 + wn * 32 + nf * 16 + l15;
    size_t rowbase = (tb0 + (size_t)(rr >> 7) * 2) * 16384 + (size_t)(rr & 127) * 128;
    int sw = (rr & 7) << 4;
#pragma unroll
    for (int ks = 0; ks < 4; ++ks) {
      int d = ks * 32 + lg * 8;
      size_t a = rowbase + (size_t)(d >> 6) * 16384 + (((d & 63) * 2) ^ sw);
      qh[nf][ks] = *(const bf16x8*)(pQh + a);
      ql[nf][ks] = *(const bf16x8*)(pQl + a);
    }
  }

  f32x4 yacc[2][4];
#pragma unroll
  for (int i = 0; i < 2; ++i)
#pragma unroll
    for (int j = 0; j < 4; ++j) yacc[i][j] = (f32x4){0.f, 0.f, 0.f, 0.f};

  auto stageK = [&](int mt) {
    size_t half = (size_t)(mt & 1) * 8192;
#pragma unroll
    for (int dt = 0; dt < 2; ++dt) {
      size_t tile = (tb0 + (size_t)(mt >> 1) * 2 + dt) * 16384 + half;
#pragma unroll
      for (int c = 0; c < 2; ++c) {
        size_t go = (size_t)c * 4096 + w * 1024 + lane * 16;
        glds16(pKh + tile + go, &Kls[dt][0][c * 4096 + w * 1024]);
        glds16(pKl + tile + go, &Kls[dt][1][c * 4096 + w * 1024]);
      }
    }
  };
  auto stageV = [&](int mt) {
    size_t tile = (tb0 + mt) * 16384;
#pragma unroll
    for (int c = 0; c < 4; ++c) {
      size_t go = (size_t)c * 4096 + w * 1024 + lane * 16;
      glds16(pVh + tile + go, &Vls[0][c * 4096 + w * 1024]);
      glds16(pVl + tile + go, &Vls[1][c * 4096 + w * 1024]);
    }
  };

  stageK(0);
  stageV(0);
  __syncthreads();

  for (int mt = 0; mt < nt; ++mt) {
    f32x4 sacc[2][2];
#pragma unroll
    for (int i = 0; i < 2; ++i)
#pragma unroll
      for (int j = 0; j < 2; ++j) sacc[i][j] = (f32x4){0.f, 0.f, 0.f, 0.f};
#pragma unroll
    for (int ks = 0; ks < 4; ++ks) {
      int d = ks * 32 + lg * 8;
      bf16x8 kh[2], kl[2];
#pragma unroll
      for (int mf = 0; mf < 2; ++mf) {
        int m = wq * 32 + mf * 16 + l15;
        int off = (m & 63) * 128 + (((d & 63) * 2) ^ ((m & 7) << 4));
        kh[mf] = *(const bf16x8*)&Kls[d >> 6][0][off];
        kl[mf] = *(const bf16x8*)&Kls[d >> 6][1][off];
      }
#pragma unroll
      for (int nf = 0; nf < 2; ++nf)
#pragma unroll
        for (int mf = 0; mf < 2; ++mf) {
          sacc[nf][mf] = __builtin_amdgcn_mfma_f32_16x16x32_bf16(
              qh[nf][ks], kh[mf], sacc[nf][mf], 0, 0, 0);
          sacc[nf][mf] = __builtin_amdgcn_mfma_f32_16x16x32_bf16(
              qh[nf][ks], kl[mf], sacc[nf][mf], 0, 0, 0);
          sacc[nf][mf] = __builtin_amdgcn_mfma_f32_16x16x32_bf16(
              ql[nf][ks], kh[mf], sacc[nf][mf], 0, 0, 0);
        }
    }
    asm volatile("s_barrier" ::: "memory");
    if (mt + 1 < nt) stageK(mt + 1);

#pragma unroll
    for (int nf = 0; nf < 2; ++nf)
#pragma unroll
      for (int mf = 0; mf < 2; ++mf)
#pragma unroll
        for (int r = 0; r < 4; ++r) {
          int nl = wn * 32 + nf * 16 + lg * 4 + r;
          int ml = wq * 32 + mf * 16 + l15;
          int diff = (n0 + nl) - (mt * 64 + ml);
          float dec = (diff >= 0) ? exp2f((float)diff * lg2) : 0.0f;
          float p = sacc[nf][mf][r] * dec;
          __bf16 h = (__bf16)p;
          int off = nl * 128 + ((ml * 2) ^ ((nl & 7) << 4));
          *(__bf16*)&Pls[0][off] = h;
          *(__bf16*)&Pls[1][off] = (__bf16)(p - (float)h);
        }
    asm volatile("s_waitcnt lgkmcnt(0)" ::: "memory");
    asm volatile("s_barrier" ::: "memory");

#pragma unroll
    for (int ks = 0; ks < 2; ++ks) {
      int mchunk = ks * 32 + lg * 8;
      bf16x8 ph[2], pl2[2], vh[4], vl2[4];
#pragma unroll
      for (int nf = 0; nf < 2; ++nf) {
        int nl = wn * 32 + nf * 16 + l15;
        int off = nl * 128 + ((mchunk * 2) ^ ((nl & 7) << 4));
        ph[nf]  = *(const bf16x8*)&Pls[0][off];
        pl2[nf] = *(const bf16x8*)&Pls[1][off];
      }
#pragma unroll
      for (int df = 0; df < 4; ++df) {
        int d = wq * 64 + df * 16 + l15;
        int off = d * 128 + ((mchunk * 2) ^ ((d & 7) << 4));
        vh[df]  = *(const bf16x8*)&Vls[0][off];
        vl2[df] = *(const bf16x8*)&Vls[1][off];
      }
#pragma unroll
      for (int nf = 0; nf < 2; ++nf)
#pragma unroll
        for (int df = 0; df < 4; ++df) {
          yacc[nf][df] = __builtin_amdgcn_mfma_f32_16x16x32_bf16(
              ph[nf], vh[df], yacc[nf][df], 0, 0, 0);
          yacc[nf][df] = __builtin_amdgcn_mfma_f32_16x16x32_bf16(
              ph[nf], vl2[df], yacc[nf][df], 0, 0, 0);
          yacc[nf][df] = __builtin_amdgcn_mfma_f32_16x16x32_bf16(
              pl2[nf], vh[df], yacc[nf][df], 0, 0, 0);
        }
    }
    asm volatile("s_barrier" ::: "memory");
    if (mt + 1 < nt) stageV(mt + 1);
    __syncthreads();
  }

  const size_t yrow0 = (size_t)(bh >> 3) * SS + n0;
  const int hcol = (bh & 7) * HDD;
#pragma unroll
  for (int nf = 0; nf < 2; ++nf)
#pragma unroll
    for (int df = 0; df < 4; ++df)
#pragma unroll
      for (int r = 0; r < 4; ++r) {
        int nl = wn * 32 + nf * 16 + lg * 4 + r;
        int d  = wq * 64 + df * 16 + l15;
        Y[(yrow0 + nl) * DM + hcol + d] = yacc[nf][df][r];
      }
}

// ---------------- GroupNorm * gate -> packed hi/lo swizzled A-operand -------
__global__ __launch_bounds__(256) void gn_gate_k(
    const float* __restrict__ Y, const float* __restrict__ w,
    const float* __restrict__ b, const float* __restrict__ G,
    char* __restrict__ ph, char* __restrict__ pl) {
  int g    = blockIdx.x * 4 + (threadIdx.x >> 6);
  int lane = threadIdx.x & 63;
  float2 v = *(const float2*)(Y + (size_t)g * HDD + lane * 2);
  float s = v.x + v.y, q = v.x * v.x + v.y * v.y;
#pragma unroll
  for (int o = 32; o > 0; o >>= 1) { s += __shfl_xor(s, o); q += __shfl_xor(q, o); }
  float mu  = s * (1.0f / HDD);
  float var = q * (1.0f / HDD) - mu * mu;
  float rs  = 1.0f / sqrtf(var + 1e-5f);
  int m   = g >> 3;
  int col = (g & 7) * HDD + lane * 2;
  float2 wv = *(const float2*)(w + col);
  float2 bv = *(const float2*)(b + col);
  float2 gv = *(const float2*)(G + (size_t)g * HDD + lane * 2);
  float ox = ((v.x - mu) * rs * wv.x + bv.x) * gv.x;
  float oy = ((v.y - mu) * rs * wv.y + bv.y) * gv.y;
  __bf16 hx = (__bf16)ox, hy = (__bf16)oy;
  bf16x2 hv, lv;
  hv[0] = hx; hv[1] = hy;
  lv[0] = (__bf16)(ox - (float)hx); lv[1] = (__bf16)(oy - (float)hy);
  size_t tb = ((size_t)(m >> 7) * (DM / 64) + (col >> 6)) * 16384;
  int off = (m & 127) * 128 + (((col & 63) * 2) ^ ((m & 7) << 4));
  *(bf16x2*)(ph + tb + off) = hv;
  *(bf16x2*)(pl + tb + off) = lv;
}

// ---------------- driver -----------------------------------------------------
extern "C" void kernel_launch(void* const* d_in, const int* in_sizes, int n_in,
                              void* d_out, int out_size, void* d_ws, size_t ws_size,
                              hipStream_t stream) {
  (void)in_sizes; (void)n_in; (void)out_size; (void)ws_size;
  const float* X0   = (const float*)d_in[0];
  const float* ln1w = (const float*)d_in[1];
  const float* ln1b = (const float*)d_in[2];
  const float* ln2w = (const float*)d_in[3];
  const float* ln2b = (const float*)d_in[4];
  const float* WQ   = (const float*)d_in[5];
  const float* WK   = (const float*)d_in[6];
  const float* WV   = (const float*)d_in[7];
  const float* gnw  = (const float*)d_in[8];
  const float* gnb  = (const float*)d_in[9];
  const float* WG   = (const float*)d_in[10];
  const float* WO   = (const float*)d_in[11];
  const float* W1   = (const float*)d_in[12];
  const float* B1   = (const float*)d_in[13];
  const float* W2   = (const float*)d_in[14];
  const float* B2   = (const float*)d_in[15];

  char* wsb = (char*)d_ws;
  const size_t MB = 1 << 20;
  float* bufA = (float*)(wsb + 0 * MB);    // X carry
  float* bufB = (float*)(wsb + 16 * MB);   // Y (WO out / FFN resid)
  float* bufE = (float*)(wsb + 32 * MB);   // V fp32
  float* bufF = (float*)(wsb + 48 * MB);   // gate
  float* bufG = (float*)(wsb + 64 * MB);   // Yh
  float* sq   = (float*)(wsb + 80 * MB);
  float* cq   = (float*)(wsb + 81 * MB);
  float* sk   = (float*)(wsb + 82 * MB);
  float* ck   = (float*)(wsb + 83 * MB);
  float* lg2g = (float*)(wsb + 84 * MB);
  char* pXh = wsb + 85 * MB;
  char* pXl = wsb + 93 * MB;
  char* pWh = wsb + 101 * MB;   // 26 MB (Q,K,V,G,O contiguous 2MB each; W1 8MB; W2 8MB)
  char* pWl = wsb + 127 * MB;   // 26 MB
  char* R   = wsb + 153 * MB;   // overlap region: attn phase vs FFN phase
  char* pFh = R;                // 32 MB (FFN)
  char* pFl = R + 32 * MB;
  char* pQh = R;                // 8 MB (attention)
  char* pQl = R + 8 * MB;
  char* pKh = R + 16 * MB;
  char* pKl = R + 24 * MB;
  char* pVh = R + 32 * MB;
  char* pVl = R + 40 * MB;
  const size_t oWQ = 0, oW1 = (size_t)10 << 20, oWO = (size_t)8 << 20,
               oW2 = (size_t)18 << 20;

  init_tables_k<<<SS, HDD, 0, stream>>>(sq, cq, sk, ck, lg2g);

  for (int i = 0; i < LN_; ++i) {
    const float* Xin = (i == 0) ? X0 : bufA;
    // pack layer weights: Q,K,V,G consecutive (2MB each), then O, W1, W2
    packw_k<<<dim3(8, 16), 256, 0, stream>>>(WQ + (size_t)i * 1048576, pWh + oWQ, pWl + oWQ, 1024, 1);
    packw_k<<<dim3(8, 16), 256, 0, stream>>>(WK + (size_t)i * 1048576, pWh + 2 * MB, pWl + 2 * MB, 1024, 1);
    packw_k<<<dim3(8, 16), 256, 0, stream>>>(WV + (size_t)i * 1048576, pWh + 4 * MB, pWl + 4 * MB, 1024, 1);
    packw_k<<<dim3(8, 16), 256, 0, stream>>>(WG + (size_t)i * 1048576, pWh + 6 * MB, pWl + 6 * MB, 1024, 0);
    packw_k<<<dim3(8, 16), 256, 0, stream>>>(WO + (size_t)i * 1048576, pWh + oWO, pWl + oWO, 1024, 0);
    packw_k<<<dim3(32, 16), 256, 0, stream>>>(W1 + (size_t)i * 4194304, pWh + oW1, pWl + oW1, 4096, 0);
    packw_k<<<dim3(8, 64), 256, 0, stream>>>(W2 + (size_t)i * 4194304, pWh + oW2, pWl + oW2, 1024, 0);

    ln_pack_k<<<RR, 256, 0, stream>>>(Xin, ln1w + i * DM, ln1b + i * DM, pXh, pXl);
    qkvg_k<<<dim3(8, 32, 4), 256, 0, stream>>>(pXh, pXl, pWh, pWl, bufE, bufF,
                                               pQh, pQl, pKh, pKl, sq, cq, sk, ck);
    vtpack_k<<<dim3(32, 16), 256, 0, stream>>>(bufE, pVh, pVl);
    mattn_k<<<dim3(32, 16), 256, 0, stream>>>(pQh, pQl, pKh, pKl, pVh, pVl, lg2g, bufG);
    gn_gate_k<<<RR * HH / 4, 256, 0, stream>>>(bufG, gnw + i * DM, gnb + i * DM,
                                               bufF, pXh, pXl);
    mgemm_k<2, 2><<<dim3(16, 32), 256, 0, stream>>>(pXh, pXl, pWh + oWO, pWl + oWO,
                                                    bufB, nullptr, Xin, nullptr, nullptr,
                                                    DM, DM);
    ln_pack_k<<<RR, 256, 0, stream>>>(bufB, ln2w + i * DM, ln2b + i * DM, pXh, pXl);
    mgemm_k<3, 4><<<dim3(32, 32), 256, 0, stream>>>(pXh, pXl, pWh + oW1, pWl + oW1,
                                                    nullptr, B1 + (size_t)i * FFN_,
                                                    nullptr, pFh, pFl, FFN_, DM);
    float* Xout = (i == LN_ - 1) ? (float*)d_out : bufA;
    mgemm_k<4, 2><<<dim3(16, 32), 256, 0, stream>>>(pFh, pFl, pWh + oW2, pWl + oW2,
                                                    Xout, B2 + (size_t)i * DM, bufB,
                                                    nullptr, nullptr, DM, FFN_);
  }
}